// Round 2
// baseline (578.924 us; speedup 1.0000x reference)
//
#include <hip/hip_runtime.h>
#include <math.h>

// Problem constants (reference: B,P,NTIME,NLATENT,NSPATIAL = 4,2,16,32,2048)
#define NB 4
#define NP 2
#define NT 16
#define NC 32
#define NX 2048

// Exact triangle packing: per e, 136 floats. Row A holds S[A,j], j=0..15-A:
// S[A,0]=G[A,A], S[A,j]=G[A,A+j]+G[A+j,A]. Row offset = A*16 - A(A-1)/2.
#define TRI_N 136

// ---------------------------------------------------------------------------
// Merged precompute (single launch; R12 measured: cuts launch overhead
// from ~69us to ~17us vs 4 separate launches):
//  blocks [0,512)    : G0p[c,e]  packed-symmetric (c=bid>>4, e=bid&15)
//  blocks [512,528)  : G1p[e]    packed-symmetric
//  blocks [528,544)  : M1t       (4096 elems)
//  blocks [544,1056) : M2        (131072 elems)
// ---------------------------------------------------------------------------
__device__ void g_body(const float* __restrict__ K,
                       const float* __restrict__ V,
                       const float* __restrict__ enc,
                       float* __restrict__ Gp,
                       int cstride, int c, int e, int tid) {
    __shared__ float sK[256], sV[256], sE[256], sW[256];
    {
        const int t = tid >> 4, A = tid & 15;
        sK[tid] = K[(t * 16 + A) * cstride + c];
        sV[tid] = V[(t * 16 + A) * cstride + c];
        sE[tid] = enc[(e * 16 + t) * 16 + A];
    }
    __syncthreads();
    {   // W[t,B] = sum_T enc[e,t,T] * V[T,B,c]
        const int t = tid >> 4, Bi = tid & 15;
        float acc = 0.f;
#pragma unroll
        for (int T = 0; T < 16; ++T) acc += sE[t * 16 + T] * sV[T * 16 + Bi];
        sW[tid] = acc;
    }
    __syncthreads();
    float gval;
    {   // G[A,B] = sum_t K[t,A,c] * W[t,B]
        const int A = tid >> 4, Bi = tid & 15;
        float acc = 0.f;
#pragma unroll
        for (int t = 0; t < 16; ++t) acc += sK[t * 16 + A] * sW[t * 16 + Bi];
        gval = acc;
    }
    __syncthreads();
    sE[tid] = gval;            // sE := full G tile
    __syncthreads();
    if (tid < TRI_N) {
        int A = 0, off = 0;
        while (A < 15 && tid >= off + (16 - A)) { off += 16 - A; ++A; }
        const int j = tid - off;
        const float v = (j == 0) ? sE[A * 16 + A]
                                 : sE[A * 16 + A + j] + sE[(A + j) * 16 + A];
        Gp[(c * 16 + e) * TRI_N + tid] = v;
    }
}

__global__ void precompute_all(const float* __restrict__ K0,
                               const float* __restrict__ V0,
                               const float* __restrict__ K1,
                               const float* __restrict__ V1,
                               const float* __restrict__ Q0,
                               const float* __restrict__ Q1,
                               const float* __restrict__ enc,
                               const float* __restrict__ dec,
                               float* __restrict__ G0p,
                               float* __restrict__ G1p,
                               float* __restrict__ M1t,
                               float* __restrict__ M2) {
    const int b = blockIdx.x;
    const int tid = threadIdx.x;
    if (b < 512) {
        g_body(K0, V0, enc, G0p, NC, b >> 4, b & 15, tid);
    } else if (b < 528) {
        g_body(K1, V1, enc, G1p, 1, 0, b - 512, tid);
    } else if (b < 544) {
        // M1t[e][E][T] = sum_t Q1[t,T] * dec[e,t,E]
        const int idx = (b - 528) * 256 + tid;           // 4096
        const int e = idx >> 8, E = (idx >> 4) & 15, T = idx & 15;
        float acc = 0.f;
#pragma unroll
        for (int t = 0; t < 16; ++t)
            acc += Q1[t * 16 + T] * dec[(e * 16 + t) * 16 + E];
        M1t[idx] = acc;
    } else {
        // M2[c][T][A][E] = sum_t Q0[t,A,c] * dec[E,t,T]
        const int idx = (b - 544) * 256 + tid;           // 131072
        const int c = idx >> 12, T = (idx >> 8) & 15,
                  A = (idx >> 4) & 15, E = idx & 15;
        float acc = 0.f;
#pragma unroll
        for (int t = 0; t < 16; ++t)
            acc += Q0[(t * 16 + A) * NC + c] * dec[(E * 16 + t) * 16 + T];
        M2[idx] = acc;
    }
}

__device__ __forceinline__ float sqrt_act(float v) {
    return copysignf(sqrtf(fabsf(v)), v);
}

// R14: SMEM weights (R13 mechanism — wave-uniform scalar loads, 0 VALU per
// weight) at FULL OCCUPANCY. R13 post-mortem: busy-time 123us == FMA floor
// (scalar path has the right inst count; readlane was ~6-8cyc, worth ~73us),
// but 58% of time was lgkmcnt stalls: weight batches don't fit SGPRs, and at
// VGPR=100 (rounds to 128-granule -> 4 waves/SIMD) phase-locked waves can't
// cover the scalar-fetch latency. SMEM has no per-weight VALU, so S=1 costs
// NOTHING in instructions (FMA floor unchanged ~91us) and halves VGPR ->
// <=64 -> 8 waves/SIMD. X kept live through stage 3 (no Y reload).
// Serial FMA chains split even/odd (S=1 removed the 2-site interleave that
// used to cover dependent-FMA latency).
#define TRIFORM_S1(GW, V, R)                                               \
    do {                                                                   \
        float tc = 0.f, td = 0.f;                                          \
        _Pragma("unroll")                                                  \
        for (int A = 0; A < 16; ++A) {                                     \
            const int koff = A * 16 - (A * (A - 1)) / 2;                   \
            float tae = 0.f, tao = 0.f;                                    \
            _Pragma("unroll")                                              \
            for (int j = 0; j < 16 - A; j += 2)                            \
                tae += (GW)[koff + j] * V[A + j];                          \
            _Pragma("unroll")                                              \
            for (int j = 1; j < 16 - A; j += 2)                            \
                tao += (GW)[koff + j] * V[A + j];                          \
            const float ta = tae + tao;                                    \
            if (A & 1) td += V[A] * ta; else tc += V[A] * ta;              \
        }                                                                  \
        R = tc + td;                                                       \
    } while (0)

// ---------------------------------------------------------------------------
// Main kernel: ONE thread per (b,p,c,x) site (S=1).
// grid = NB*NP*NC*(NX/256) = 2048 blocks of 256 = 8 blocks/CU = 32 waves/CU.
// __launch_bounds__(256, 8): 8 waves/EU -> forces VGPR <= 64 allocation.
// ---------------------------------------------------------------------------
__global__ __launch_bounds__(256, 8) void site_kernel(
    const float* __restrict__ x,
    const float* __restrict__ a,
    const float* __restrict__ w,
    const float* __restrict__ G0p,
    const float* __restrict__ G1p,
    const float* __restrict__ M1t,
    const float* __restrict__ M2,
    float* __restrict__ out) {
    const int tid = threadIdx.x;
    const int bid = blockIdx.x;
    const int xc = bid & 7;               // 8 x-chunks of 256
    const int c  = (bid >> 3) & 31;
    const int bp = bid >> 8;              // [0, NB*NP)
    const int x0 = (xc << 8) + tid;
    const float* xb = x + (bp * NT * NC + c) * NX;

    // ---- load the site's 16-vector (coalesced); stays live to stage 3 ----
    float X[16];
#pragma unroll
    for (int t = 0; t < 16; ++t) X[t] = xb[t * NC * NX + x0];

    // ======== stage 0: h[e] = sqrt_act( X^T Sym(G0[c,e]) X ) ========
    float h[16];
    {
        const float* __restrict__ g0 = G0p + c * (16 * TRI_N);
#pragma unroll 1
        for (int e = 0; e < 16; ++e) {
            const float* __restrict__ gw = g0 + e * TRI_N;   // uniform -> SGPR
            float r;
            TRIFORM_S1(gw, X, r);
            h[e] = sqrt_act(r);
        }
    }

    // ======== stages 1+2 fused:
    //   p_e = a[e,x] * sqrt_act( h^T Sym(G1[e]) h )
    //   b2[E] += p_e * ( sum_T h_T * M1t[e,E,T] )
    float b2[16];
#pragma unroll
    for (int E = 0; E < 16; ++E) b2[E] = 0.f;
#pragma unroll 1
    for (int e = 0; e < 16; ++e) {
        const float* __restrict__ g1 = G1p + e * TRI_N;      // uniform -> SGPR
        const float* __restrict__ m1 = M1t + e * 256;        // uniform -> SGPR
        const float ae = a[e * NX + x0];
        float r;
        TRIFORM_S1(g1, h, r);
        const float pe = ae * sqrt_act(r);
#pragma unroll
        for (int E = 0; E < 16; ++E) {
            float se = 0.f, so = 0.f;
#pragma unroll
            for (int T = 0; T < 16; T += 2) se += m1[E * 16 + T] * h[T];
#pragma unroll
            for (int T = 1; T < 16; T += 2) so += m1[E * 16 + T] * h[T];
            b2[E] += pe * (se + so);
        }
    }
    // h dead here; X still live (serves as Y below — no reload).

    // ======== stage 3: y = sum_T w[T,x] * ( X^T M2[c,T] b2 ) ========
    float y = 0.f;
    {
        const float* __restrict__ m2c = M2 + c * 4096;
#pragma unroll 1
        for (int T = 0; T < 16; ++T) {
            const float* __restrict__ mt = m2c + T * 256;    // uniform -> SGPR
            const float wt = w[T * NX + x0];
            float tc = 0.f, td = 0.f;
#pragma unroll
            for (int A = 0; A < 16; ++A) {
                float se = 0.f, so = 0.f;
#pragma unroll
                for (int E = 0; E < 16; E += 2) se += mt[A * 16 + E] * b2[E];
#pragma unroll
                for (int E = 1; E < 16; E += 2) so += mt[A * 16 + E] * b2[E];
                const float s = se + so;
                if (A & 1) td += X[A] * s; else tc += X[A] * s;
            }
            y += wt * (tc + td);
        }
    }

    // ---- reduce over the block, one atomic per block ----
#pragma unroll
    for (int off = 32; off > 0; off >>= 1) y += __shfl_down(y, off);
    __shared__ float red[4];
    if ((tid & 63) == 0) red[tid >> 6] = y;
    __syncthreads();
    if (tid == 0) {
        atomicAdd(&out[bp * NC + c], red[0] + red[1] + red[2] + red[3]);
    }
}

extern "C" void kernel_launch(void* const* d_in, const int* in_sizes, int n_in,
                              void* d_out, int out_size, void* d_ws, size_t ws_size,
                              hipStream_t stream) {
    const float* x   = (const float*)d_in[0];
    const float* K0  = (const float*)d_in[1];
    const float* Q0  = (const float*)d_in[2];
    const float* V0  = (const float*)d_in[3];
    const float* K1  = (const float*)d_in[4];
    const float* Q1  = (const float*)d_in[5];
    const float* V1  = (const float*)d_in[6];
    const float* enc = (const float*)d_in[7];
    const float* dec = (const float*)d_in[8];
    const float* a   = (const float*)d_in[9];
    const float* w   = (const float*)d_in[10];
    float* out = (float*)d_out;

    float* G0p = (float*)d_ws;                // 32*16*136 = 69632 floats
    float* G1p = G0p + NC * 16 * TRI_N;       // 16*136 = 2176
    float* M1t = G1p + 16 * TRI_N;            // 4096
    float* M2  = M1t + 4096;                  // 131072
    // total ws: 206976 floats ~= 0.83 MB

    // out must be zeroed every call (harness re-poisons with 0xAA)
    hipMemsetAsync(d_out, 0, (size_t)out_size * sizeof(float), stream);

    precompute_all<<<1056, 256, 0, stream>>>(K0, V0, K1, V1, Q0, Q1,
                                             enc, dec, G0p, G1p, M1t, M2);

    const int nblocks = NB * NP * NC * (NX / 256);  // 2048
    site_kernel<<<nblocks, 256, 0, stream>>>(x, a, w, G0p, G1p, M1t, M2, out);
}

// Round 3
// 371.879 us; speedup vs baseline: 1.5568x; 1.5568x over previous
//
#include <hip/hip_runtime.h>
#include <math.h>

// Problem constants (reference: B,P,NTIME,NLATENT,NSPATIAL = 4,2,16,32,2048)
#define NB 4
#define NP 2
#define NT 16
#define NC 32
#define NX 2048

// R15 packing: padded symmetric-triangle, 4-float-ALIGNED rows so LDS reads
// are ds_read_b128. Row A holds S[A,j], j=0..15-A (S[A,0]=G[A,A],
// S[A,j]=G[A,A+j]+G[A+j,A]), zero-padded to a multiple of 4 floats.
// Row start ps_row(A) = 8g(9-g) + (A&3)(16-4g), g=A>>2. Total 160 floats/e.
#define TRI_P 160

__host__ __device__ constexpr int ps_row(int A) {
    const int g = A >> 2;
    return 8 * g * (9 - g) + (A & 3) * (16 - 4 * g);
}

// ---------------------------------------------------------------------------
// Merged precompute (single launch):
//  blocks [0,512)    : G0p[c,e]  padded-packed-symmetric (c=bid>>4, e=bid&15)
//  blocks [512,528)  : G1p[e]    padded-packed-symmetric
//  blocks [528,544)  : M1t       (4096 elems)
//  blocks [544,1056) : M2        (131072 elems)
// ---------------------------------------------------------------------------
__device__ void g_body(const float* __restrict__ K,
                       const float* __restrict__ V,
                       const float* __restrict__ enc,
                       float* __restrict__ Gp,
                       int cstride, int c, int e, int tid) {
    __shared__ float sK[256], sV[256], sE[256], sW[256];
    {
        const int t = tid >> 4, A = tid & 15;
        sK[tid] = K[(t * 16 + A) * cstride + c];
        sV[tid] = V[(t * 16 + A) * cstride + c];
        sE[tid] = enc[(e * 16 + t) * 16 + A];
    }
    __syncthreads();
    {   // W[t,B] = sum_T enc[e,t,T] * V[T,B,c]
        const int t = tid >> 4, Bi = tid & 15;
        float acc = 0.f;
#pragma unroll
        for (int T = 0; T < 16; ++T) acc += sE[t * 16 + T] * sV[T * 16 + Bi];
        sW[tid] = acc;
    }
    __syncthreads();
    float gval;
    {   // G[A,B] = sum_t K[t,A,c] * W[t,B]
        const int A = tid >> 4, Bi = tid & 15;
        float acc = 0.f;
#pragma unroll
        for (int t = 0; t < 16; ++t) acc += sK[t * 16 + A] * sW[t * 16 + Bi];
        gval = acc;
    }
    __syncthreads();
    sE[tid] = gval;            // sE := full G tile
    __syncthreads();
    if (tid < TRI_P) {
        int A = 0;
        while (A < 15 && tid >= ps_row(A + 1)) ++A;
        const int j = tid - ps_row(A);
        float v = 0.f;                         // zero pad slots
        if (j < 16 - A)
            v = (j == 0) ? sE[A * 16 + A]
                         : sE[A * 16 + A + j] + sE[(A + j) * 16 + A];
        Gp[(c * 16 + e) * TRI_P + tid] = v;
    }
}

__global__ void precompute_all(const float* __restrict__ K0,
                               const float* __restrict__ V0,
                               const float* __restrict__ K1,
                               const float* __restrict__ V1,
                               const float* __restrict__ Q0,
                               const float* __restrict__ Q1,
                               const float* __restrict__ enc,
                               const float* __restrict__ dec,
                               float* __restrict__ G0p,
                               float* __restrict__ G1p,
                               float* __restrict__ M1t,
                               float* __restrict__ M2) {
    const int b = blockIdx.x;
    const int tid = threadIdx.x;
    if (b < 512) {
        g_body(K0, V0, enc, G0p, NC, b >> 4, b & 15, tid);
    } else if (b < 528) {
        g_body(K1, V1, enc, G1p, 1, 0, b - 512, tid);
    } else if (b < 544) {
        // M1t[e][E][T] = sum_t Q1[t,T] * dec[e,t,E]
        const int idx = (b - 528) * 256 + tid;           // 4096
        const int e = idx >> 8, E = (idx >> 4) & 15, T = idx & 15;
        float acc = 0.f;
#pragma unroll
        for (int t = 0; t < 16; ++t)
            acc += Q1[t * 16 + T] * dec[(e * 16 + t) * 16 + E];
        M1t[idx] = acc;
    } else {
        // M2[c][T][A][E] = sum_t Q0[t,A,c] * dec[E,t,T]
        const int idx = (b - 544) * 256 + tid;           // 131072
        const int c = idx >> 12, T = (idx >> 8) & 15,
                  A = (idx >> 4) & 15, E = idx & 15;
        float acc = 0.f;
#pragma unroll
        for (int t = 0; t < 16; ++t)
            acc += Q0[(t * 16 + A) * NC + c] * dec[(E * 16 + t) * 16 + T];
        M2[idx] = acc;
    }
}

__device__ __forceinline__ float sqrt_act(float v) {
    return copysignf(sqrtf(fabsf(v)), v);
}

// R15: weight delivery via LDS BROADCAST ds_read_b128 (wave-uniform address:
// conflict-free, 0 VALU per weight, DS pipe co-issues in VALU bubbles).
// R13 proved the 0-VALU weight path hits the FMA floor (busy 123us) but
// s_load L2 latency (~250cy) stalled 58%; LDS latency (~120cy, many
// outstanding) is coverable at 4 waves/SIMD. R14 proved 8 waves/SIMD is
// unreachable (64-VGPR cap -> array spills -> 379MB scratch traffic).
// Pad FMAs (4*q+k >= 16-A) are skipped at compile time: FLOP count == R11.
#define TRIFORM_L2(SW, V0, V1, R0, R1)                                     \
    do {                                                                   \
        float tc0 = 0.f, td0 = 0.f, tc1 = 0.f, td1 = 0.f;                  \
        _Pragma("unroll")                                                  \
        for (int A = 0; A < 16; ++A) {                                     \
            float ta0 = 0.f, ta1 = 0.f;                                    \
            _Pragma("unroll")                                              \
            for (int q = 0; q < (16 - A + 3) / 4; ++q) {                   \
                const float4 wv =                                          \
                    *(const float4*)((SW) + ps_row(A) + 4 * q);            \
                _Pragma("unroll")                                          \
                for (int k = 0; k < 4; ++k) {                              \
                    if (4 * q + k < 16 - A) {                              \
                        const float rw = ((const float*)&wv)[k];           \
                        ta0 += rw * (V0)[A + 4 * q + k];                   \
                        ta1 += rw * (V1)[A + 4 * q + k];                   \
                    }                                                      \
                }                                                          \
            }                                                              \
            if (A & 1) { td0 += (V0)[A] * ta0; td1 += (V1)[A] * ta1; }     \
            else       { tc0 += (V0)[A] * ta0; tc1 += (V1)[A] * ta1; }     \
        }                                                                  \
        R0 = tc0 + td0;  R1 = tc1 + td1;                                   \
    } while (0)

// ---------------------------------------------------------------------------
// Main kernel: one thread per TWO (b,p,c,x) sites (x0, x0+256).
// grid = NB*NP*NC*(NX/512) = 1024 blocks of 256 = 4 blocks/CU.
// One reused 26.6KB LDS weight buffer, staged per stage (4 blocks/CU ->
// 106KB < 160KB). VGPR target ~100-112 (<=128 -> 4 waves/SIMD).
// ---------------------------------------------------------------------------
__global__ __launch_bounds__(256) void site_kernel(
    const float* __restrict__ x,
    const float* __restrict__ a,
    const float* __restrict__ w,
    const float* __restrict__ G0p,
    const float* __restrict__ G1p,
    const float* __restrict__ M1t,
    const float* __restrict__ M2,
    float* __restrict__ out) {
    __shared__ __align__(16) float swt[16 * TRI_P + 4096];  // 6656 floats
    __shared__ float red[4];

    const int tid = threadIdx.x;
    const int bid = blockIdx.x;
    const int xc = bid & 3;
    const int c  = (bid >> 2) & 31;
    const int bp = bid >> 7;              // [0, NB*NP)
    const int x0 = (xc << 9) + tid;       // site 0; site 1 at x0+256
    const float* xb = x + (bp * NT * NC + c) * NX;

    // ---- stage 0 weights -> LDS (640 float4) ----
    {
        const float4* src = (const float4*)(G0p + c * (16 * TRI_P));
        float4* dst = (float4*)swt;
#pragma unroll
        for (int i = tid; i < 16 * TRI_P / 4; i += 256) dst[i] = src[i];
    }

    // ---- load both sites' 16-vectors (coalesced) ----
    float X0[16], X1[16];
#pragma unroll
    for (int t = 0; t < 16; ++t) {
        X0[t] = xb[t * NC * NX + x0];
        X1[t] = xb[t * NC * NX + x0 + 256];
    }
    __syncthreads();

    // ======== stage 0: h[e] = sqrt_act( X^T Sym(G0[c,e]) X ) ========
    float h0[16], h1[16];
#pragma unroll 1
    for (int e = 0; e < 16; ++e) {
        const float* gw = swt + e * TRI_P;          // uniform -> broadcast
        float r0, r1;
        TRIFORM_L2(gw, X0, X1, r0, r1);
        h0[e] = sqrt_act(r0);
        h1[e] = sqrt_act(r1);
    }
    // X dead here (re-loaded for the final stage).
    __syncthreads();                                // all waves done with G0

    // ---- stage 1+2 weights -> LDS: G1p (640 f4) + M1t (1024 f4) ----
    {
        const float4* s1 = (const float4*)G1p;
        const float4* s2 = (const float4*)M1t;
        float4* dst = (float4*)swt;
#pragma unroll
        for (int i = tid; i < 640; i += 256) dst[i] = s1[i];
#pragma unroll
        for (int i = tid; i < 1024; i += 256) dst[640 + i] = s2[i];
    }
    __syncthreads();

    // ======== stages 1+2 fused:
    //   p_e = a[e,x] * sqrt_act( h^T Sym(G1[e]) h )
    //   b2[E] += p_e * ( sum_T h_T * M1t[e,E,T] )
    float b20[16], b21[16];
#pragma unroll
    for (int E = 0; E < 16; ++E) { b20[E] = 0.f; b21[E] = 0.f; }
#pragma unroll 1
    for (int e = 0; e < 16; ++e) {
        const float* g1 = swt + e * TRI_P;          // uniform -> broadcast
        const float* m1 = swt + 16 * TRI_P + e * 256;
        const float ae0 = a[e * NX + x0];
        const float ae1 = a[e * NX + x0 + 256];
        float r0, r1;
        TRIFORM_L2(g1, h0, h1, r0, r1);
        const float pe0 = ae0 * sqrt_act(r0);
        const float pe1 = ae1 * sqrt_act(r1);
#pragma unroll
        for (int E = 0; E < 16; ++E) {
            float s0 = 0.f, s1 = 0.f;
#pragma unroll
            for (int q = 0; q < 4; ++q) {
                const float4 wv = *(const float4*)(m1 + E * 16 + 4 * q);
#pragma unroll
                for (int k = 0; k < 4; ++k) {
                    const float rw = ((const float*)&wv)[k];
                    s0 += rw * h0[4 * q + k];
                    s1 += rw * h1[4 * q + k];
                }
            }
            b20[E] += pe0 * s0;
            b21[E] += pe1 * s1;
        }
    }
    // h dead here.
    __syncthreads();                                // all waves done with G1/M1t

    // ---- stage 3 weights -> LDS (1024 f4); Y reload overlaps the staging ----
    {
        const float4* src = (const float4*)(M2 + c * 4096);
        float4* dst = (float4*)swt;
#pragma unroll
        for (int i = tid; i < 1024; i += 256) dst[i] = src[i];
    }
    // launder base pointer only (blocks X->Y CSE that caused the R6 spills)
    const float* xr = xb;
    asm volatile("" : "+r"(xr));
    float Y0[16], Y1[16];
#pragma unroll
    for (int t = 0; t < 16; ++t) {
        Y0[t] = xr[t * NC * NX + x0];
        Y1[t] = xr[t * NC * NX + x0 + 256];
    }
    __syncthreads();

    // ======== stage 3: y = sum_T w[T,x] * ( Y^T M2[c,T] b2 ) ========
    float y0 = 0.f, y1 = 0.f;
#pragma unroll 1
    for (int T = 0; T < 16; ++T) {
        const float* mt = swt + T * 256;            // uniform -> broadcast
        const float wt0 = w[T * NX + x0];
        const float wt1 = w[T * NX + x0 + 256];
        float c0 = 0.f, d0 = 0.f, c1 = 0.f, d1 = 0.f;
#pragma unroll
        for (int A = 0; A < 16; ++A) {
            float s0 = 0.f, s1 = 0.f;
#pragma unroll
            for (int q = 0; q < 4; ++q) {
                const float4 wv = *(const float4*)(mt + A * 16 + 4 * q);
#pragma unroll
                for (int k = 0; k < 4; ++k) {
                    const float rw = ((const float*)&wv)[k];
                    s0 += rw * b20[4 * q + k];
                    s1 += rw * b21[4 * q + k];
                }
            }
            if (A & 1) { d0 += Y0[A] * s0; d1 += Y1[A] * s1; }
            else       { c0 += Y0[A] * s0; c1 += Y1[A] * s1; }
        }
        y0 += wt0 * (c0 + d0);
        y1 += wt1 * (c1 + d1);
    }

    // ---- reduce over the block, one atomic per block ----
    float y = y0 + y1;
#pragma unroll
    for (int off = 32; off > 0; off >>= 1) y += __shfl_down(y, off);
    if ((tid & 63) == 0) red[tid >> 6] = y;
    __syncthreads();
    if (tid == 0) {
        atomicAdd(&out[bp * NC + c], red[0] + red[1] + red[2] + red[3]);
    }
}

extern "C" void kernel_launch(void* const* d_in, const int* in_sizes, int n_in,
                              void* d_out, int out_size, void* d_ws, size_t ws_size,
                              hipStream_t stream) {
    const float* x   = (const float*)d_in[0];
    const float* K0  = (const float*)d_in[1];
    const float* Q0  = (const float*)d_in[2];
    const float* V0  = (const float*)d_in[3];
    const float* K1  = (const float*)d_in[4];
    const float* Q1  = (const float*)d_in[5];
    const float* V1  = (const float*)d_in[6];
    const float* enc = (const float*)d_in[7];
    const float* dec = (const float*)d_in[8];
    const float* a   = (const float*)d_in[9];
    const float* w   = (const float*)d_in[10];
    float* out = (float*)d_out;

    float* G0p = (float*)d_ws;                // 32*16*160 = 81920 floats
    float* G1p = G0p + NC * 16 * TRI_P;       // 16*160 = 2560
    float* M1t = G1p + 16 * TRI_P;            // 4096
    float* M2  = M1t + 4096;                  // 131072
    // total ws: 219648 floats ~= 0.88 MB

    // out must be zeroed every call (harness re-poisons with 0xAA)
    hipMemsetAsync(d_out, 0, (size_t)out_size * sizeof(float), stream);

    precompute_all<<<1056, 256, 0, stream>>>(K0, V0, K1, V1, Q0, Q1,
                                             enc, dec, G0p, G1p, M1t, M2);

    const int nblocks = NB * NP * NC * (NX / 512);  // 1024
    site_kernel<<<nblocks, 256, 0, stream>>>(x, a, w, G0p, G1p, M1t, M2, out);
}

// Round 4
// 192.543 us; speedup vs baseline: 3.0067x; 1.9314x over previous
//
#include <hip/hip_runtime.h>
#include <math.h>

// Problem constants (reference: B,P,NTIME,NLATENT,NSPATIAL = 4,2,16,32,2048)
#define NB 4
#define NP 2
#define NT 16
#define NC 32
#define NX 2048

// ---------------------------------------------------------------------------
// R16: MFMA rewrite. Every heavy op is out[16] = M(16x16) . in[16] batched
// over x -> v_mfma_f32_16x16x32_f16 with 16 x-sites per fragment column.
// fp32 accuracy via f16 hi/lo split FUSED into K=32:
//   A-frag = [Mh | Ml] (16x32);  mfma(A,[Vh;Vh]) + mfma(A,[Vl;Vl])
//   = (Mh+Ml)(Vh+Vl)  -- full 4-term split product, 2 MFMAs per matvec.
// Slot->k convention: k = g*8 + j (g=lane>>4, j=elem). Any bijection works
// as long as A tables and B packs use the SAME one (hardware pairs A slot
// (g,j) with B slot (g,j); permutation cancels in the contraction).
// C/D layout (HW-verified m89): col=lane&15, row=(lane>>4)*4+reg.
// Weight-delivery lesson ledger: readlane = VALU-bound (R11 254us);
// s_load = scalar-latency-bound (R13); LDS broadcast = DS-pipe-bound (R15).
// MFMA reads weights as fragments: delivery cost folds into the matrix op.
// ---------------------------------------------------------------------------

typedef _Float16 f16x8 __attribute__((ext_vector_type(8)));
typedef float f32x4 __attribute__((ext_vector_type(4)));

__device__ __forceinline__ unsigned short f16hi_bits(float v) {
    _Float16 h = (_Float16)v;
    return __builtin_bit_cast(unsigned short, h);
}
__device__ __forceinline__ unsigned short f16lo_bits(float v) {
    _Float16 h = (_Float16)v;
    _Float16 l = (_Float16)(v - (float)h);
    return __builtin_bit_cast(unsigned short, l);
}
__device__ __forceinline__ f16x8 frag_cast(uint4 u) {
    return __builtin_bit_cast(f16x8, u);
}
__device__ __forceinline__ float sqrt_act(float v) {
    return copysignf(sqrtf(fabsf(v)), v);
}

// ---------------------------------------------------------------------------
// Precompute. G matrices via the validated g_body GEMM; all weight matrices
// are emitted as per-lane A-fragments: lane holds row=lane&15, slots j=0..7
// at k = (lane>>4)*8 + j;  k<16 -> f16hi(M[row][k]), k>=16 -> f16lo(M[row][k-16]).
// One uint4 (8 halfs) per lane per matrix = 1KB/matrix.
//  blocks [0,512)   : G0 frags  (c=b>>4, e=b&15)
//  blocks [512,528) : G1 frags
//  blocks [528,532) : M1t frags (16 mats x 64 lanes)
//  blocks [532,660) : M2 frags  (512 mats x 64 lanes)
// ---------------------------------------------------------------------------
__device__ void g_body(const float* __restrict__ K,
                       const float* __restrict__ V,
                       const float* __restrict__ enc,
                       uint4* __restrict__ dst,   // frag base for this matrix
                       int cstride, int c, int e, int tid) {
    __shared__ float sK[256], sV[256], sE[256], sW[256];
    {
        const int t = tid >> 4, A = tid & 15;
        sK[tid] = K[(t * 16 + A) * cstride + c];
        sV[tid] = V[(t * 16 + A) * cstride + c];
        sE[tid] = enc[(e * 16 + t) * 16 + A];
    }
    __syncthreads();
    {   // W[t,B] = sum_T enc[e,t,T] * V[T,B,c]
        const int t = tid >> 4, Bi = tid & 15;
        float acc = 0.f;
#pragma unroll
        for (int T = 0; T < 16; ++T) acc += sE[t * 16 + T] * sV[T * 16 + Bi];
        sW[tid] = acc;
    }
    __syncthreads();
    float gval;
    {   // G[A,B] = sum_t K[t,A,c] * W[t,B]
        const int A = tid >> 4, Bi = tid & 15;
        float acc = 0.f;
#pragma unroll
        for (int t = 0; t < 16; ++t) acc += sK[t * 16 + A] * sW[t * 16 + Bi];
        gval = acc;
    }
    __syncthreads();
    sE[tid] = gval;            // sE := full G tile (quadratic form: X^T G X —
    __syncthreads();           // no symmetrization needed, orientation-immune)
    if (tid < 64) {
        const int row = tid & 15, g = tid >> 4;
        unsigned int dw[4];
#pragma unroll
        for (int d = 0; d < 4; ++d) {
            const int c0 = 8 * (g & 1) + 2 * d;
            const float v0 = sE[row * 16 + c0];
            const float v1 = sE[row * 16 + c0 + 1];
            const unsigned short s0 = (g < 2) ? f16hi_bits(v0) : f16lo_bits(v0);
            const unsigned short s1 = (g < 2) ? f16hi_bits(v1) : f16lo_bits(v1);
            dw[d] = (unsigned)s0 | ((unsigned)s1 << 16);
        }
        dst[tid] = make_uint4(dw[0], dw[1], dw[2], dw[3]);
    }
}

__global__ void precompute_all(const float* __restrict__ K0,
                               const float* __restrict__ V0,
                               const float* __restrict__ K1,
                               const float* __restrict__ V1,
                               const float* __restrict__ Q0,
                               const float* __restrict__ Q1,
                               const float* __restrict__ enc,
                               const float* __restrict__ dec,
                               uint4* __restrict__ AF0,
                               uint4* __restrict__ AFG1,
                               uint4* __restrict__ AFM1,
                               uint4* __restrict__ AFM2) {
    const int b = blockIdx.x;
    const int tid = threadIdx.x;
    if (b < 512) {
        g_body(K0, V0, enc, AF0 + b * 64, NC, b >> 4, b & 15, tid);
    } else if (b < 528) {
        g_body(K1, V1, enc, AFG1 + (b - 512) * 64, 1, 0, b - 512, tid);
    } else if (b < 532) {
        // M1t[e][E][T] = sum_t Q1[t,T] * dec[e,t,E];  A rows=E, k=T
        const int idx = (b - 528) * 256 + tid;           // [0,1024)
        const int e = idx >> 6, lane = idx & 63;
        const int row = lane & 15, g = lane >> 4;
        unsigned int dw[4];
#pragma unroll
        for (int d = 0; d < 4; ++d) {
            unsigned short s01[2];
#pragma unroll
            for (int hh = 0; hh < 2; ++hh) {
                const int cc = 8 * (g & 1) + 2 * d + hh;  // = T index
                float acc = 0.f;
#pragma unroll
                for (int t = 0; t < 16; ++t)
                    acc += Q1[t * 16 + cc] * dec[(e * 16 + t) * 16 + row];
                s01[hh] = (g < 2) ? f16hi_bits(acc) : f16lo_bits(acc);
            }
            dw[d] = (unsigned)s01[0] | ((unsigned)s01[1] << 16);
        }
        AFM1[idx] = make_uint4(dw[0], dw[1], dw[2], dw[3]);
    } else {
        // M2[c][T][A][E] = sum_t Q0[t,A,c] * dec[E,t,T];  A-frag rows=A, k=E
        const int idx = (b - 532) * 256 + tid;           // [0,32768)
        const int mat = idx >> 6, lane = idx & 63;
        const int c = mat >> 4, T = mat & 15;
        const int row = lane & 15, g = lane >> 4;        // row = A
        unsigned int dw[4];
#pragma unroll
        for (int d = 0; d < 4; ++d) {
            unsigned short s01[2];
#pragma unroll
            for (int hh = 0; hh < 2; ++hh) {
                const int cc = 8 * (g & 1) + 2 * d + hh;  // = E index
                float acc = 0.f;
#pragma unroll
                for (int t = 0; t < 16; ++t)
                    acc += Q0[(t * 16 + row) * NC + c] * dec[(cc * 16 + t) * 16 + T];
                s01[hh] = (g < 2) ? f16hi_bits(acc) : f16lo_bits(acc);
            }
            dw[d] = (unsigned)s01[0] | ((unsigned)s01[1] << 16);
        }
        AFM2[idx] = make_uint4(dw[0], dw[1], dw[2], dw[3]);
    }
}

// ---------------------------------------------------------------------------
// Main kernel: one WAVE handles two 16-column x-tiles of one (bp,c).
// Block = 4 waves = 8 xtiles = 128 x. grid = 8*32*16 = 4096 blocks; bid
// ordered so consecutive blocks share (bp,c) -> weight frags L2-hot.
// Per matvec: 2 MFMAs (shared A-frag across both xtiles). Dots use the
// verified C layout (Xc rows 4g+i). h and b2 bounce through a per-wave
// padded LDS strip to re-shape C-frag rows -> B-frag k-rows.
// ---------------------------------------------------------------------------
__global__ __launch_bounds__(256) void site_kernel(
    const float* __restrict__ x,
    const float* __restrict__ a,
    const float* __restrict__ w,
    const uint4* __restrict__ AF0,
    const uint4* __restrict__ AFG1,
    const uint4* __restrict__ AFM1,
    const uint4* __restrict__ AFM2,
    float* __restrict__ out) {
    __shared__ float hlds[4][2][16 * 17];
    __shared__ float red[4];

    const int tid = threadIdx.x;
    const int lane = tid & 63, wid = tid >> 6;
    const int col = lane & 15, g = lane >> 4;
    const int kb = (g & 1) * 8;           // B-pack row base (k = g*8+j mod 16)
    const int bid = blockIdx.x;
    const int xg = bid & 15;
    const int c  = (bid >> 4) & 31;
    const int bp = bid >> 9;
    const int xA = xg * 128 + wid * 32 + col;
    const int xB = xA + 16;
    const float* xb = x + (bp * NT * NC + c) * NX;

    // ---- X: B-pack rows kb..kb+7 (f16 hi/lo) + C-rows 4g..4g+3 (fp32) ----
    f16x8 XhA, XlA, XhB, XlB;
    float XcA[4], XcB[4];
#pragma unroll
    for (int j = 0; j < 8; ++j) {
        const float vA = xb[(kb + j) * NC * NX + xA];
        const float vB = xb[(kb + j) * NC * NX + xB];
        const _Float16 ha = (_Float16)vA;
        const _Float16 hb = (_Float16)vB;
        XhA[j] = ha; XlA[j] = (_Float16)(vA - (float)ha);
        XhB[j] = hb; XlB[j] = (_Float16)(vB - (float)hb);
    }
#pragma unroll
    for (int i = 0; i < 4; ++i) {
        XcA[i] = xb[(4 * g + i) * NC * NX + xA];
        XcB[i] = xb[(4 * g + i) * NC * NX + xB];
    }

    // ======== stage 0: h[e] = sqrt_act( X^T G0[c,e] X ) ========
    {
        const uint4* af0 = AF0 + (c * 16) * 64 + lane;
        uint4 cur = af0[0];
#pragma unroll 1
        for (int e = 0; e < 16; ++e) {
            const uint4 nxt = af0[((e + 1) & 15) * 64];
            const f16x8 af = frag_cast(cur);
            f32x4 Ca = {0.f, 0.f, 0.f, 0.f}, Cb = {0.f, 0.f, 0.f, 0.f};
            Ca = __builtin_amdgcn_mfma_f32_16x16x32_f16(af, XhA, Ca, 0, 0, 0);
            Ca = __builtin_amdgcn_mfma_f32_16x16x32_f16(af, XlA, Ca, 0, 0, 0);
            Cb = __builtin_amdgcn_mfma_f32_16x16x32_f16(af, XhB, Cb, 0, 0, 0);
            Cb = __builtin_amdgcn_mfma_f32_16x16x32_f16(af, XlB, Cb, 0, 0, 0);
            float sA = XcA[0]*Ca[0] + XcA[1]*Ca[1] + XcA[2]*Ca[2] + XcA[3]*Ca[3];
            float sB = XcB[0]*Cb[0] + XcB[1]*Cb[1] + XcB[2]*Cb[2] + XcB[3]*Cb[3];
            sA += __shfl_xor(sA, 16); sA += __shfl_xor(sA, 32);
            sB += __shfl_xor(sB, 16); sB += __shfl_xor(sB, 32);
            if (lane < 16) {
                hlds[wid][0][lane * 17 + e] = sqrt_act(sA);
                hlds[wid][1][lane * 17 + e] = sqrt_act(sB);
            }
            cur = nxt;
        }
    }
    // X packs dead after stage0; XcA/XcB stay live for stage 3.

    // ---- h -> B-packs (f16 hi/lo) + C-row copies (fp32) from LDS ----
    f16x8 hHA, hLA, hHB, hLB;
    float hcA[4], hcB[4];
#pragma unroll
    for (int j = 0; j < 8; ++j) {
        const float vA = hlds[wid][0][col * 17 + kb + j];
        const float vB = hlds[wid][1][col * 17 + kb + j];
        const _Float16 ha = (_Float16)vA;
        const _Float16 hb = (_Float16)vB;
        hHA[j] = ha; hLA[j] = (_Float16)(vA - (float)ha);
        hHB[j] = hb; hLB[j] = (_Float16)(vB - (float)hb);
    }
#pragma unroll
    for (int i = 0; i < 4; ++i) {
        hcA[i] = hlds[wid][0][col * 17 + 4 * g + i];
        hcB[i] = hlds[wid][1][col * 17 + 4 * g + i];
    }

    // ======== stages 1+2: b2[E] = sum_e pe * (M1t[e] . h),
    //          pe = a[e,x] * sqrt_act( h^T G1[e] h ) ========
    f32x4 b2A = {0.f, 0.f, 0.f, 0.f}, b2B = {0.f, 0.f, 0.f, 0.f};
    {
        const uint4* afg = AFG1 + lane;
        const uint4* afm = AFM1 + lane;
        uint4 curG = afg[0], curM = afm[0];
#pragma unroll 1
        for (int e = 0; e < 16; ++e) {
            const uint4 nxtG = afg[((e + 1) & 15) * 64];
            const uint4 nxtM = afm[((e + 1) & 15) * 64];
            const float aeA = a[e * NX + xA];
            const float aeB = a[e * NX + xB];
            const f16x8 ag = frag_cast(curG);
            f32x4 Ca = {0.f, 0.f, 0.f, 0.f}, Cb = {0.f, 0.f, 0.f, 0.f};
            Ca = __builtin_amdgcn_mfma_f32_16x16x32_f16(ag, hHA, Ca, 0, 0, 0);
            Ca = __builtin_amdgcn_mfma_f32_16x16x32_f16(ag, hLA, Ca, 0, 0, 0);
            Cb = __builtin_amdgcn_mfma_f32_16x16x32_f16(ag, hHB, Cb, 0, 0, 0);
            Cb = __builtin_amdgcn_mfma_f32_16x16x32_f16(ag, hLB, Cb, 0, 0, 0);
            float sA = hcA[0]*Ca[0] + hcA[1]*Ca[1] + hcA[2]*Ca[2] + hcA[3]*Ca[3];
            float sB = hcB[0]*Cb[0] + hcB[1]*Cb[1] + hcB[2]*Cb[2] + hcB[3]*Cb[3];
            sA += __shfl_xor(sA, 16); sA += __shfl_xor(sA, 32);
            sB += __shfl_xor(sB, 16); sB += __shfl_xor(sB, 32);
            const float peA = aeA * sqrt_act(sA);
            const float peB = aeB * sqrt_act(sB);
            const f16x8 am = frag_cast(curM);
            f32x4 Ua = {0.f, 0.f, 0.f, 0.f}, Ub = {0.f, 0.f, 0.f, 0.f};
            Ua = __builtin_amdgcn_mfma_f32_16x16x32_f16(am, hHA, Ua, 0, 0, 0);
            Ua = __builtin_amdgcn_mfma_f32_16x16x32_f16(am, hLA, Ua, 0, 0, 0);
            Ub = __builtin_amdgcn_mfma_f32_16x16x32_f16(am, hHB, Ub, 0, 0, 0);
            Ub = __builtin_amdgcn_mfma_f32_16x16x32_f16(am, hLB, Ub, 0, 0, 0);
            b2A += Ua * peA;
            b2B += Ub * peB;
            curG = nxtG; curM = nxtM;
        }
    }

    // ---- b2 C-frag -> LDS -> B-packs (rows=E match stage-3 contraction) ----
#pragma unroll
    for (int i = 0; i < 4; ++i) {
        hlds[wid][0][col * 17 + 4 * g + i] = b2A[i];
        hlds[wid][1][col * 17 + 4 * g + i] = b2B[i];
    }
    f16x8 bHA, bLA, bHB, bLB;
#pragma unroll
    for (int j = 0; j < 8; ++j) {
        const float vA = hlds[wid][0][col * 17 + kb + j];
        const float vB = hlds[wid][1][col * 17 + kb + j];
        const _Float16 ha = (_Float16)vA;
        const _Float16 hb = (_Float16)vB;
        bHA[j] = ha; bLA[j] = (_Float16)(vA - (float)ha);
        bHB[j] = hb; bLB[j] = (_Float16)(vB - (float)hb);
    }

    // ======== stage 3: y = sum_T w[T,x] * ( X^T (M2[c,T] . b2) ) ========
    float yA = 0.f, yB = 0.f;
    {
        const uint4* afm2 = AFM2 + (c * 16) * 64 + lane;
        uint4 cur = afm2[0];
#pragma unroll 1
        for (int T = 0; T < 16; ++T) {
            const uint4 nxt = afm2[((T + 1) & 15) * 64];
            const f16x8 am = frag_cast(cur);
            f32x4 Za = {0.f, 0.f, 0.f, 0.f}, Zb = {0.f, 0.f, 0.f, 0.f};
            Za = __builtin_amdgcn_mfma_f32_16x16x32_f16(am, bHA, Za, 0, 0, 0);
            Za = __builtin_amdgcn_mfma_f32_16x16x32_f16(am, bLA, Za, 0, 0, 0);
            Zb = __builtin_amdgcn_mfma_f32_16x16x32_f16(am, bHB, Zb, 0, 0, 0);
            Zb = __builtin_amdgcn_mfma_f32_16x16x32_f16(am, bLB, Zb, 0, 0, 0);
            float sA = XcA[0]*Za[0] + XcA[1]*Za[1] + XcA[2]*Za[2] + XcA[3]*Za[3];
            float sB = XcB[0]*Zb[0] + XcB[1]*Zb[1] + XcB[2]*Zb[2] + XcB[3]*Zb[3];
            sA += __shfl_xor(sA, 16); sA += __shfl_xor(sA, 32);
            sB += __shfl_xor(sB, 16); sB += __shfl_xor(sB, 32);
            yA += w[T * NX + xA] * sA;
            yB += w[T * NX + xB] * sB;
            cur = nxt;
        }
    }

    // ---- reduce: y replicated across groups; sum the 16 columns ----
    float y = yA + yB;
    y += __shfl_xor(y, 1); y += __shfl_xor(y, 2);
    y += __shfl_xor(y, 4); y += __shfl_xor(y, 8);
    if (lane == 0) red[wid] = y;
    __syncthreads();
    if (tid == 0) {
        atomicAdd(&out[bp * NC + c], red[0] + red[1] + red[2] + red[3]);
    }
}

extern "C" void kernel_launch(void* const* d_in, const int* in_sizes, int n_in,
                              void* d_out, int out_size, void* d_ws, size_t ws_size,
                              hipStream_t stream) {
    const float* x   = (const float*)d_in[0];
    const float* K0  = (const float*)d_in[1];
    const float* Q0  = (const float*)d_in[2];
    const float* V0  = (const float*)d_in[3];
    const float* K1  = (const float*)d_in[4];
    const float* Q1  = (const float*)d_in[5];
    const float* V1  = (const float*)d_in[6];
    const float* enc = (const float*)d_in[7];
    const float* dec = (const float*)d_in[8];
    const float* a   = (const float*)d_in[9];
    const float* w   = (const float*)d_in[10];
    float* out = (float*)d_out;

    // Frag tables (uint4 each = 8 packed halfs/lane):
    uint4* AF0  = (uint4*)d_ws;          // 512 mats * 64 = 32768 (512KB)
    uint4* AFG1 = AF0  + 512 * 64;       // 16 mats  (16KB)
    uint4* AFM1 = AFG1 + 16 * 64;        // 16 mats  (16KB)
    uint4* AFM2 = AFM1 + 16 * 64;        // 512 mats (512KB)
    // total ws ~= 1.03 MB

    // out must be zeroed every call (harness re-poisons with 0xAA)
    hipMemsetAsync(d_out, 0, (size_t)out_size * sizeof(float), stream);

    precompute_all<<<660, 256, 0, stream>>>(K0, V0, K1, V1, Q0, Q1,
                                            enc, dec, AF0, AFG1, AFM1, AFM2);

    const int nblocks = NB * NP * NC * (NX / 128);  // 8*32*16 = 4096
    site_kernel<<<nblocks, 256, 0, stream>>>(x, a, w, AF0, AFG1, AFM1, AFM2, out);
}

// Round 6
// 190.360 us; speedup vs baseline: 3.0412x; 1.0115x over previous
//
#include <hip/hip_runtime.h>
#include <math.h>

// Problem constants (reference: B,P,NTIME,NLATENT,NSPATIAL = 4,2,16,32,2048)
#define NB 4
#define NP 2
#define NT 16
#define NC 32
#define NX 2048

// ---------------------------------------------------------------------------
// R16 engine (validated: absmax 2.4e-7, 114us): every heavy op is
// out[16] = M(16x16) . in[16] batched over x via v_mfma_f32_16x16x32_f16,
// fp32 accuracy from the fused f16 hi/lo split: A=[Mh|Ml], two MFMAs with
// B=[Vh;Vh],[Vl;Vl] give (Mh+Ml)(Vh+Vl).
// R18 = R16 + the two VALUE-SAFE R17 changes only:
//  - pointer-walk prefetch over padded tables (addressing-only, loads the
//    same bytes -> cannot change results)
//  - stage-3 group-reduce deferred out of the T-loop (pure reassociation,
//    <=2x error growth, 5x threshold headroom)
// REVERTED: ds_swizzle+permlane32_swap cross_reduce. R17 failed at 2.6e-4;
// triage: permlane32_swap MUTATES BOTH OPERANDS -- passing the same value
// for both (aliased regs) degenerates the swap. Ledger: dual-output lane
// primitives with aliased operands are unsafe from HIP source. The proven
// __shfl_xor(16)+__shfl_xor(32) pair is restored everywhere.
// Weight-delivery ledger: readlane=VALU-bound(254us R11); s_load=scalar-
// latency-bound(R13); LDS broadcast=DS-pipe-bound(R15); MFMA frags win.
// ---------------------------------------------------------------------------

typedef _Float16 f16x8 __attribute__((ext_vector_type(8)));
typedef float f32x4 __attribute__((ext_vector_type(4)));

__device__ __forceinline__ unsigned short f16hi_bits(float v) {
    _Float16 h = (_Float16)v;
    return __builtin_bit_cast(unsigned short, h);
}
__device__ __forceinline__ unsigned short f16lo_bits(float v) {
    _Float16 h = (_Float16)v;
    _Float16 l = (_Float16)(v - (float)h);
    return __builtin_bit_cast(unsigned short, l);
}
__device__ __forceinline__ f16x8 frag_cast(uint4 u) {
    return __builtin_bit_cast(f16x8, u);
}
__device__ __forceinline__ float sqrt_act(float v) {
    return copysignf(sqrtf(fabsf(v)), v);
}
// Sum over the 4 lane-groups (proven R16 path). Result in ALL lanes.
__device__ __forceinline__ float xgrp_sum(float s) {
    s += __shfl_xor(s, 16);
    s += __shfl_xor(s, 32);
    return s;
}

// ---------------------------------------------------------------------------
// Precompute (validated R16). Weight matrices emitted as per-lane
// A-fragments: lane holds row=lane&15, slots j=0..7 at k=(lane>>4)*8+j;
// k<16 -> f16hi(M[row][k]), k>=16 -> f16lo(M[row][k-16]).
//  blocks [0,512)   : G0 frags  (c=b>>4, e=b&15)
//  blocks [512,528) : G1 frags
//  blocks [528,532) : M1t frags
//  blocks [532,660) : M2 frags
//  block  660       : zero pad matrix (prefetch overrun target)
// ---------------------------------------------------------------------------
__device__ void g_body(const float* __restrict__ K,
                       const float* __restrict__ V,
                       const float* __restrict__ enc,
                       uint4* __restrict__ dst,
                       int cstride, int c, int e, int tid) {
    __shared__ float sK[256], sV[256], sE[256], sW[256];
    {
        const int t = tid >> 4, A = tid & 15;
        sK[tid] = K[(t * 16 + A) * cstride + c];
        sV[tid] = V[(t * 16 + A) * cstride + c];
        sE[tid] = enc[(e * 16 + t) * 16 + A];
    }
    __syncthreads();
    {   // W[t,B] = sum_T enc[e,t,T] * V[T,B,c]
        const int t = tid >> 4, Bi = tid & 15;
        float acc = 0.f;
#pragma unroll
        for (int T = 0; T < 16; ++T) acc += sE[t * 16 + T] * sV[T * 16 + Bi];
        sW[tid] = acc;
    }
    __syncthreads();
    float gval;
    {   // G[A,B] = sum_t K[t,A,c] * W[t,B]
        const int A = tid >> 4, Bi = tid & 15;
        float acc = 0.f;
#pragma unroll
        for (int t = 0; t < 16; ++t) acc += sK[t * 16 + A] * sW[t * 16 + Bi];
        gval = acc;
    }
    __syncthreads();
    sE[tid] = gval;            // quadratic form: orientation-immune
    __syncthreads();
    if (tid < 64) {
        const int row = tid & 15, g = tid >> 4;
        unsigned int dw[4];
#pragma unroll
        for (int d = 0; d < 4; ++d) {
            const int c0 = 8 * (g & 1) + 2 * d;
            const float v0 = sE[row * 16 + c0];
            const float v1 = sE[row * 16 + c0 + 1];
            const unsigned short s0 = (g < 2) ? f16hi_bits(v0) : f16lo_bits(v0);
            const unsigned short s1 = (g < 2) ? f16hi_bits(v1) : f16lo_bits(v1);
            dw[d] = (unsigned)s0 | ((unsigned)s1 << 16);
        }
        dst[tid] = make_uint4(dw[0], dw[1], dw[2], dw[3]);
    }
}

__global__ void precompute_all(const float* __restrict__ K0,
                               const float* __restrict__ V0,
                               const float* __restrict__ K1,
                               const float* __restrict__ V1,
                               const float* __restrict__ Q0,
                               const float* __restrict__ Q1,
                               const float* __restrict__ enc,
                               const float* __restrict__ dec,
                               uint4* __restrict__ AF0,
                               uint4* __restrict__ AFG1,
                               uint4* __restrict__ AFM1,
                               uint4* __restrict__ AFM2) {
    const int b = blockIdx.x;
    const int tid = threadIdx.x;
    if (b < 512) {
        g_body(K0, V0, enc, AF0 + b * 64, NC, b >> 4, b & 15, tid);
    } else if (b < 528) {
        g_body(K1, V1, enc, AFG1 + (b - 512) * 64, 1, 0, b - 512, tid);
    } else if (b < 532) {
        // M1t[e][E][T] = sum_t Q1[t,T] * dec[e,t,E];  A rows=E, k=T
        const int idx = (b - 528) * 256 + tid;           // [0,1024)
        const int e = idx >> 6, lane = idx & 63;
        const int row = lane & 15, g = lane >> 4;
        unsigned int dw[4];
#pragma unroll
        for (int d = 0; d < 4; ++d) {
            unsigned short s01[2];
#pragma unroll
            for (int hh = 0; hh < 2; ++hh) {
                const int cc = 8 * (g & 1) + 2 * d + hh;  // = T index
                float acc = 0.f;
#pragma unroll
                for (int t = 0; t < 16; ++t)
                    acc += Q1[t * 16 + cc] * dec[(e * 16 + t) * 16 + row];
                s01[hh] = (g < 2) ? f16hi_bits(acc) : f16lo_bits(acc);
            }
            dw[d] = (unsigned)s01[0] | ((unsigned)s01[1] << 16);
        }
        AFM1[idx] = make_uint4(dw[0], dw[1], dw[2], dw[3]);
    } else if (b < 660) {
        // M2[c][T][A][E] = sum_t Q0[t,A,c] * dec[E,t,T];  A-frag rows=A, k=E
        const int idx = (b - 532) * 256 + tid;           // [0,32768)
        const int mat = idx >> 6, lane = idx & 63;
        const int c = mat >> 4, T = mat & 15;
        const int row = lane & 15, g = lane >> 4;        // row = A
        unsigned int dw[4];
#pragma unroll
        for (int d = 0; d < 4; ++d) {
            unsigned short s01[2];
#pragma unroll
            for (int hh = 0; hh < 2; ++hh) {
                const int cc = 8 * (g & 1) + 2 * d + hh;  // = E index
                float acc = 0.f;
#pragma unroll
                for (int t = 0; t < 16; ++t)
                    acc += Q0[(t * 16 + row) * NC + c] * dec[(cc * 16 + t) * 16 + T];
                s01[hh] = (g < 2) ? f16hi_bits(acc) : f16lo_bits(acc);
            }
            dw[d] = (unsigned)s01[0] | ((unsigned)s01[1] << 16);
        }
        AFM2[idx] = make_uint4(dw[0], dw[1], dw[2], dw[3]);
    } else {
        // zero pad matrix after AFM2 (target of the last stage-3 prefetch)
        if (tid < 64) AFM2[512 * 64 + tid] = make_uint4(0u, 0u, 0u, 0u);
    }
}

// ---------------------------------------------------------------------------
// Main kernel: one WAVE handles two 16-column x-tiles of one (bp,c).
// Block = 4 waves = 8 xtiles = 128 x. grid = 4096 blocks; consecutive
// blocks share (bp,c) -> weight frags L2-hot. Frag prefetches walk padded
// tables (inter-table overruns land in the next table; zeroed pad after
// AFM2) -> no wrap-mask VALU. C/D layout: col=lane&15, row=4g+reg.
// ---------------------------------------------------------------------------
__global__ __launch_bounds__(256) void site_kernel(
    const float* __restrict__ x,
    const float* __restrict__ a,
    const float* __restrict__ w,
    const uint4* __restrict__ AF0,
    const uint4* __restrict__ AFG1,
    const uint4* __restrict__ AFM1,
    const uint4* __restrict__ AFM2,
    float* __restrict__ out) {
    __shared__ float hlds[4][2][16 * 17];
    __shared__ float red[4];

    const int tid = threadIdx.x;
    const int lane = tid & 63, wid = tid >> 6;
    const int col = lane & 15, g = lane >> 4;
    const int kb = (g & 1) * 8;           // B-pack row base (k = g*8+j mod 16)
    const int bid = blockIdx.x;
    const int xg = bid & 15;
    const int c  = (bid >> 4) & 31;
    const int bp = bid >> 9;
    const int xA = xg * 128 + wid * 32 + col;
    const float* xb = x + (bp * NT * NC + c) * NX;

    // ---- X: B-pack rows kb..kb+7 (f16 hi/lo) + C-rows 4g..4g+3 (fp32) ----
    f16x8 XhA, XlA, XhB, XlB;
    float XcA[4], XcB[4];
#pragma unroll
    for (int j = 0; j < 8; ++j) {
        const float vA = xb[(kb + j) * NC * NX + xA];
        const float vB = xb[(kb + j) * NC * NX + xA + 16];
        const _Float16 ha = (_Float16)vA;
        const _Float16 hb = (_Float16)vB;
        XhA[j] = ha; XlA[j] = (_Float16)(vA - (float)ha);
        XhB[j] = hb; XlB[j] = (_Float16)(vB - (float)hb);
    }
#pragma unroll
    for (int i = 0; i < 4; ++i) {
        XcA[i] = xb[(4 * g + i) * NC * NX + xA];
        XcB[i] = xb[(4 * g + i) * NC * NX + xA + 16];
    }

    // ======== stage 0: h[e] = sqrt_act( X^T G0[c,e] X ) ========
    {
        const uint4* p0 = AF0 + (c * 16) * 64 + lane;
        uint4 cur = p0[0];
#pragma unroll 1
        for (int e = 0; e < 16; ++e) {
            p0 += 64;
            const uint4 nxt = p0[0];
            const f16x8 af = frag_cast(cur);
            f32x4 Ca = {0.f, 0.f, 0.f, 0.f}, Cb = {0.f, 0.f, 0.f, 0.f};
            Ca = __builtin_amdgcn_mfma_f32_16x16x32_f16(af, XhA, Ca, 0, 0, 0);
            Ca = __builtin_amdgcn_mfma_f32_16x16x32_f16(af, XlA, Ca, 0, 0, 0);
            Cb = __builtin_amdgcn_mfma_f32_16x16x32_f16(af, XhB, Cb, 0, 0, 0);
            Cb = __builtin_amdgcn_mfma_f32_16x16x32_f16(af, XlB, Cb, 0, 0, 0);
            float sA = XcA[0]*Ca[0] + XcA[1]*Ca[1] + XcA[2]*Ca[2] + XcA[3]*Ca[3];
            float sB = XcB[0]*Cb[0] + XcB[1]*Cb[1] + XcB[2]*Cb[2] + XcB[3]*Cb[3];
            sA = xgrp_sum(sA);
            sB = xgrp_sum(sB);
            if (lane < 16) {
                hlds[wid][0][lane * 17 + e] = sqrt_act(sA);
                hlds[wid][1][lane * 17 + e] = sqrt_act(sB);
            }
            cur = nxt;
        }
    }
    // X packs dead after stage0; XcA/XcB stay live for stage 3.

    // ---- h -> B-packs (f16 hi/lo) + C-row copies (fp32) from LDS ----
    f16x8 hHA, hLA, hHB, hLB;
    float hcA[4], hcB[4];
#pragma unroll
    for (int j = 0; j < 8; ++j) {
        const float vA = hlds[wid][0][col * 17 + kb + j];
        const float vB = hlds[wid][1][col * 17 + kb + j];
        const _Float16 ha = (_Float16)vA;
        const _Float16 hb = (_Float16)vB;
        hHA[j] = ha; hLA[j] = (_Float16)(vA - (float)ha);
        hHB[j] = hb; hLB[j] = (_Float16)(vB - (float)hb);
    }
#pragma unroll
    for (int i = 0; i < 4; ++i) {
        hcA[i] = hlds[wid][0][col * 17 + 4 * g + i];
        hcB[i] = hlds[wid][1][col * 17 + 4 * g + i];
    }

    // ======== stages 1+2: b2[E] = sum_e pe * (M1t[e] . h),
    //          pe = a[e,x] * sqrt_act( h^T G1[e] h ) ========
    f32x4 b2A = {0.f, 0.f, 0.f, 0.f}, b2B = {0.f, 0.f, 0.f, 0.f};
    {
        const uint4* pG = AFG1 + lane;
        const uint4* pM = AFM1 + lane;
        uint4 curG = pG[0], curM = pM[0];
        const float* pa = a;
#pragma unroll 1
        for (int e = 0; e < 16; ++e) {
            pG += 64; pM += 64;
            const uint4 nxtG = pG[0];
            const uint4 nxtM = pM[0];
            const float aeA = pa[xA];
            const float aeB = pa[xA + 16];
            pa += NX;
            const f16x8 ag = frag_cast(curG);
            f32x4 Ca = {0.f, 0.f, 0.f, 0.f}, Cb = {0.f, 0.f, 0.f, 0.f};
            Ca = __builtin_amdgcn_mfma_f32_16x16x32_f16(ag, hHA, Ca, 0, 0, 0);
            Ca = __builtin_amdgcn_mfma_f32_16x16x32_f16(ag, hLA, Ca, 0, 0, 0);
            Cb = __builtin_amdgcn_mfma_f32_16x16x32_f16(ag, hHB, Cb, 0, 0, 0);
            Cb = __builtin_amdgcn_mfma_f32_16x16x32_f16(ag, hLB, Cb, 0, 0, 0);
            float sA = hcA[0]*Ca[0] + hcA[1]*Ca[1] + hcA[2]*Ca[2] + hcA[3]*Ca[3];
            float sB = hcB[0]*Cb[0] + hcB[1]*Cb[1] + hcB[2]*Cb[2] + hcB[3]*Cb[3];
            sA = xgrp_sum(sA);
            sB = xgrp_sum(sB);
            const float peA = aeA * sqrt_act(sA);
            const float peB = aeB * sqrt_act(sB);
            const f16x8 am = frag_cast(curM);
            f32x4 Ua = {0.f, 0.f, 0.f, 0.f}, Ub = {0.f, 0.f, 0.f, 0.f};
            Ua = __builtin_amdgcn_mfma_f32_16x16x32_f16(am, hHA, Ua, 0, 0, 0);
            Ua = __builtin_amdgcn_mfma_f32_16x16x32_f16(am, hLA, Ua, 0, 0, 0);
            Ub = __builtin_amdgcn_mfma_f32_16x16x32_f16(am, hHB, Ub, 0, 0, 0);
            Ub = __builtin_amdgcn_mfma_f32_16x16x32_f16(am, hLB, Ub, 0, 0, 0);
            b2A += Ua * peA;
            b2B += Ub * peB;
            curG = nxtG; curM = nxtM;
        }
    }

    // ---- b2 C-frag -> LDS -> B-packs (rows=E match stage-3 contraction) ----
#pragma unroll
    for (int i = 0; i < 4; ++i) {
        hlds[wid][0][col * 17 + 4 * g + i] = b2A[i];
        hlds[wid][1][col * 17 + 4 * g + i] = b2B[i];
    }
    f16x8 bHA, bLA, bHB, bLB;
#pragma unroll
    for (int j = 0; j < 8; ++j) {
        const float vA = hlds[wid][0][col * 17 + kb + j];
        const float vB = hlds[wid][1][col * 17 + kb + j];
        const _Float16 ha = (_Float16)vA;
        const _Float16 hb = (_Float16)vB;
        bHA[j] = ha; bLA[j] = (_Float16)(vA - (float)ha);
        bHB[j] = hb; bLB[j] = (_Float16)(vB - (float)hb);
    }

    // ======== stage 3: y = sum_T w[T,x] * ( X^T (M2[c,T] . b2) ) ========
    // Group-reduce DEFERRED: w[T,x] is identical across the 4 lane-groups
    // (xA depends on col only), so linearity lets the group-sum commute out
    // of the T-loop: one xgrp_sum after, instead of 16 serial 2-shfl chains.
    float yA = 0.f, yB = 0.f;
    {
        const uint4* p2 = AFM2 + (c * 16) * 64 + lane;
        uint4 cur = p2[0];
        const float* pw = w;
#pragma unroll 1
        for (int T = 0; T < 16; ++T) {
            p2 += 64;
            const uint4 nxt = p2[0];
            const f16x8 am = frag_cast(cur);
            f32x4 Za = {0.f, 0.f, 0.f, 0.f}, Zb = {0.f, 0.f, 0.f, 0.f};
            Za = __builtin_amdgcn_mfma_f32_16x16x32_f16(am, bHA, Za, 0, 0, 0);
            Za = __builtin_amdgcn_mfma_f32_16x16x32_f16(am, bLA, Za, 0, 0, 0);
            Zb = __builtin_amdgcn_mfma_f32_16x16x32_f16(am, bHB, Zb, 0, 0, 0);
            Zb = __builtin_amdgcn_mfma_f32_16x16x32_f16(am, bLB, Zb, 0, 0, 0);
            const float sA = XcA[0]*Za[0] + XcA[1]*Za[1] + XcA[2]*Za[2] + XcA[3]*Za[3];
            const float sB = XcB[0]*Zb[0] + XcB[1]*Zb[1] + XcB[2]*Zb[2] + XcB[3]*Zb[3];
            yA += pw[xA] * sA;
            yB += pw[xA + 16] * sB;
            pw += NX;
            cur = nxt;
        }
    }

    // ---- reduce: groups once (deferred), then the 16 columns ----
    float y = xgrp_sum(yA + yB);
    y += __shfl_xor(y, 1); y += __shfl_xor(y, 2);
    y += __shfl_xor(y, 4); y += __shfl_xor(y, 8);
    if (lane == 0) red[wid] = y;
    __syncthreads();
    if (tid == 0) {
        atomicAdd(&out[bp * NC + c], red[0] + red[1] + red[2] + red[3]);
    }
}

extern "C" void kernel_launch(void* const* d_in, const int* in_sizes, int n_in,
                              void* d_out, int out_size, void* d_ws, size_t ws_size,
                              hipStream_t stream) {
    const float* x   = (const float*)d_in[0];
    const float* K0  = (const float*)d_in[1];
    const float* Q0  = (const float*)d_in[2];
    const float* V0  = (const float*)d_in[3];
    const float* K1  = (const float*)d_in[4];
    const float* Q1  = (const float*)d_in[5];
    const float* V1  = (const float*)d_in[6];
    const float* enc = (const float*)d_in[7];
    const float* dec = (const float*)d_in[8];
    const float* a   = (const float*)d_in[9];
    const float* w   = (const float*)d_in[10];
    float* out = (float*)d_out;

    // Frag tables (uint4 each = 8 packed halfs/lane), contiguous so each
    // table's pointer-walk overrun lands in the next table; one ZEROED pad
    // matrix after AFM2 covers the final table's overrun.
    uint4* AF0  = (uint4*)d_ws;          // 512 mats * 64 = 32768 (512KB)
    uint4* AFG1 = AF0  + 512 * 64;       // 16 mats  (16KB)
    uint4* AFM1 = AFG1 + 16 * 64;        // 16 mats  (16KB)
    uint4* AFM2 = AFM1 + 16 * 64;        // 512 mats (512KB) + 1 pad (1KB)
    // total ws ~= 1.04 MB

    // out must be zeroed every call (harness re-poisons with 0xAA)
    hipMemsetAsync(d_out, 0, (size_t)out_size * sizeof(float), stream);

    precompute_all<<<661, 256, 0, stream>>>(K0, V0, K1, V1, Q0, Q1,
                                            enc, dec, AF0, AFG1, AFM1, AFM2);

    const int nblocks = NB * NP * NC * (NX / 128);  // 8*32*16 = 4096
    site_kernel<<<nblocks, 256, 0, stream>>>(x, a, w, AF0, AFG1, AFM1, AFM2, out);
}

// Round 8
// 179.775 us; speedup vs baseline: 3.2203x; 1.0589x over previous
//
#include <hip/hip_runtime.h>
#include <math.h>

// Problem constants (reference: B,P,NTIME,NLATENT,NSPATIAL = 4,2,16,32,2048)
#define NB 4
#define NP 2
#define NT 16
#define NC 32
#define NX 2048
#define HS 20   // LDS per-column stride (floats): 16B-aligned reads, bank-spread

// ---------------------------------------------------------------------------
// R19 (resubmit; R7 bench was an infra failure — container never ran it):
// 32x32x16 MFMA with STACKED E-PAIRS. A=[M_2m;M_2m+1] (32x16), B=in
// (16k x 32 cols) -> one 4-pass MFMA quartet covers 2 matrices x 32 sites.
//   4 passes: (Ah,Bh)(Ah,Bl)(Al,Bh)(Al,Bl) = exact (Mh+Ml)(Vh+Vl).
// One x-site per lane (col=lane&31): group redundancy 4x->2x, ONE
// shfl_xor(32) per e (was 2 serial), glue per lane halves, 8 iters/stage.
// Layouts: C: col=lane&31, row=(reg&3)+8(reg>>2)+4(lane>>5) [HW-verified
// m74/m101]. A: row=lane&31, k=(lane>>5)*8+j. B: col=lane&31, same k.
// (Same slot-convention family R16 validated end-to-end at 16x16.)
// Ledger: readlane=VALU-bound(R11); s_load=latency-bound(R13); LDS
// broadcast=DS-bound(R15); 16x16 MFMA=glue-bound at 26% MfmaUtil (R16-18).
// ---------------------------------------------------------------------------

typedef _Float16 f16x8 __attribute__((ext_vector_type(8)));
typedef float f32x16 __attribute__((ext_vector_type(16)));

__device__ __forceinline__ unsigned short f16hi_bits(float v) {
    _Float16 h = (_Float16)v;
    return __builtin_bit_cast(unsigned short, h);
}
__device__ __forceinline__ unsigned short f16lo_bits(float v) {
    _Float16 h = (_Float16)v;
    _Float16 l = (_Float16)(v - (float)h);
    return __builtin_bit_cast(unsigned short, l);
}
__device__ __forceinline__ f16x8 frag_cast(uint4 u) {
    return __builtin_bit_cast(f16x8, u);
}
__device__ __forceinline__ float sqrt_act(float v) {
    return copysignf(sqrtf(fabsf(v)), v);
}
__device__ __forceinline__ f32x16 zero16() {
    f32x16 z;
#pragma unroll
    for (int i = 0; i < 16; ++i) z[i] = 0.f;
    return z;
}

// ---------------------------------------------------------------------------
// Precompute. Pair-frags: for pair m, A-rows 0-15 = matrix 2m, rows 16-31 =
// matrix 2m+1. Per pair: 128 uint4 = [hi-part 64 lanes][lo-part 64 lanes];
// lane holds row=lane&31, 8 halfs at k=(lane>>5)*8+j.
//  blocks [0,256)   : G0 pairs (c=b>>3, m=b&7)
//  blocks [256,264) : G1 pairs
//  blocks [264,272) : M1t pairs
//  blocks [272,528) : M2 pairs (c=(b-272)>>3, m=&7)
//  block  528       : zero pad pair
// ---------------------------------------------------------------------------
__device__ void g_compute(const float* __restrict__ K,
                          const float* __restrict__ V,
                          const float* __restrict__ enc,
                          int cstride, int c, int e, int tid,
                          float* sK, float* sV, float* sE, float* sW,
                          float* outG) {
    {
        const int t = tid >> 4, A = tid & 15;
        sK[tid] = K[(t * 16 + A) * cstride + c];
        sV[tid] = V[(t * 16 + A) * cstride + c];
        sE[tid] = enc[(e * 16 + t) * 16 + A];
    }
    __syncthreads();
    {   // W[t,B] = sum_T enc[e,t,T] * V[T,B,c]
        const int t = tid >> 4, Bi = tid & 15;
        float acc = 0.f;
#pragma unroll
        for (int T = 0; T < 16; ++T) acc += sE[t * 16 + T] * sV[T * 16 + Bi];
        sW[tid] = acc;
    }
    __syncthreads();
    {   // G[A,B] = sum_t K[t,A,c] * W[t,B]   (quadratic form: orientation-immune)
        const int A = tid >> 4, Bi = tid & 15;
        float acc = 0.f;
#pragma unroll
        for (int t = 0; t < 16; ++t) acc += sK[t * 16 + A] * sW[t * 16 + Bi];
        outG[tid] = acc;
    }
    __syncthreads();
}

__device__ void emit_pair(const float* sGa, const float* sGb,
                          uint4* __restrict__ dst, int tid) {
    if (tid < 128) {
        const int part = tid >> 6, lane = tid & 63;
        const int row32 = lane & 31, g = lane >> 5;
        const float* src = (row32 & 16) ? sGb : sGa;
        const int row = row32 & 15;
        unsigned dw[4];
#pragma unroll
        for (int d = 0; d < 4; ++d) {
            const float v0 = src[row * 16 + g * 8 + 2 * d];
            const float v1 = src[row * 16 + g * 8 + 2 * d + 1];
            const unsigned short s0 = part ? f16lo_bits(v0) : f16hi_bits(v0);
            const unsigned short s1 = part ? f16lo_bits(v1) : f16hi_bits(v1);
            dw[d] = (unsigned)s0 | ((unsigned)s1 << 16);
        }
        dst[part * 64 + lane] = make_uint4(dw[0], dw[1], dw[2], dw[3]);
    }
}

__global__ __launch_bounds__(256) void precompute_all(
    const float* __restrict__ K0, const float* __restrict__ V0,
    const float* __restrict__ K1, const float* __restrict__ V1,
    const float* __restrict__ Q0, const float* __restrict__ Q1,
    const float* __restrict__ enc, const float* __restrict__ dec,
    uint4* __restrict__ AF0, uint4* __restrict__ AFG1,
    uint4* __restrict__ AFM1, uint4* __restrict__ AFM2) {
    __shared__ float sK[256], sV[256], sE[256], sW[256], sGa[256], sGb[256];
    const int b = blockIdx.x, tid = threadIdx.x;
    if (b < 256) {
        const int c = b >> 3, m = b & 7;
        g_compute(K0, V0, enc, NC, c, 2 * m,     tid, sK, sV, sE, sW, sGa);
        g_compute(K0, V0, enc, NC, c, 2 * m + 1, tid, sK, sV, sE, sW, sGb);
        emit_pair(sGa, sGb, AF0 + (c * 8 + m) * 128, tid);
    } else if (b < 264) {
        const int m = b - 256;
        g_compute(K1, V1, enc, 1, 0, 2 * m,     tid, sK, sV, sE, sW, sGa);
        g_compute(K1, V1, enc, 1, 0, 2 * m + 1, tid, sK, sV, sE, sW, sGb);
        emit_pair(sGa, sGb, AFG1 + m * 128, tid);
    } else if (b < 272) {
        // M1t[e][E][T] = sum_t Q1[t,T]*dec[e,t,E]; pair rows=E, k=T
        const int m = b - 264;
        if (tid < 128) {
            const int part = tid >> 6, lane = tid & 63;
            const int row32 = lane & 31, g = lane >> 5;
            const int e = 2 * m + (row32 >> 4), E = row32 & 15;
            unsigned dw[4];
#pragma unroll
            for (int d = 0; d < 4; ++d) {
                unsigned short s01[2];
#pragma unroll
                for (int hh = 0; hh < 2; ++hh) {
                    const int T = g * 8 + 2 * d + hh;
                    float acc = 0.f;
#pragma unroll
                    for (int t = 0; t < 16; ++t)
                        acc += Q1[t * 16 + T] * dec[(e * 16 + t) * 16 + E];
                    s01[hh] = part ? f16lo_bits(acc) : f16hi_bits(acc);
                }
                dw[d] = (unsigned)s01[0] | ((unsigned)s01[1] << 16);
            }
            AFM1[m * 128 + part * 64 + lane] = make_uint4(dw[0], dw[1], dw[2], dw[3]);
        }
    } else if (b < 528) {
        // M2[c][T][A][E] = sum_t Q0[t,A,c]*dec[E,t,T]; pair rows=A (T-pair), k=E
        const int idx = b - 272;
        const int c = idx >> 3, m = idx & 7;
        if (tid < 128) {
            const int part = tid >> 6, lane = tid & 63;
            const int row32 = lane & 31, g = lane >> 5;
            const int T = 2 * m + (row32 >> 4), A = row32 & 15;
            unsigned dw[4];
#pragma unroll
            for (int d = 0; d < 4; ++d) {
                unsigned short s01[2];
#pragma unroll
                for (int hh = 0; hh < 2; ++hh) {
                    const int E = g * 8 + 2 * d + hh;
                    float acc = 0.f;
#pragma unroll
                    for (int t = 0; t < 16; ++t)
                        acc += Q0[(t * 16 + A) * NC + c] * dec[(E * 16 + t) * 16 + T];
                    s01[hh] = part ? f16lo_bits(acc) : f16hi_bits(acc);
                }
                dw[d] = (unsigned)s01[0] | ((unsigned)s01[1] << 16);
            }
            AFM2[(c * 8 + m) * 128 + part * 64 + lane] =
                make_uint4(dw[0], dw[1], dw[2], dw[3]);
        }
    } else {
        if (tid < 128) AFM2[256 * 128 + tid] = make_uint4(0u, 0u, 0u, 0u);
    }
}

// ---------------------------------------------------------------------------
// Main kernel: one WAVE = 32 x-sites (one per lane, col=lane&31) of one
// (bp,c). Block = 4 waves = 128 x. grid = 8*32*16 = 4096; consecutive
// blocks share (bp,c) -> frag tables L2/L1-hot (16KB per c-table).
// Per pair-iter: load 2 frags (Ah,Al), 4 MFMA, dots vs C-copy, 2 shfl_xor32,
// 2 sqrt. h and b2 bounce through per-wave LDS strip (stride HS=20).
// ---------------------------------------------------------------------------
__global__ __launch_bounds__(256) void site_kernel(
    const float* __restrict__ x,
    const float* __restrict__ a,
    const float* __restrict__ w,
    const uint4* __restrict__ AF0,
    const uint4* __restrict__ AFG1,
    const uint4* __restrict__ AFM1,
    const uint4* __restrict__ AFM2,
    float* __restrict__ out) {
    __shared__ float hlds[4][32 * HS];
    __shared__ float red[4];

    const int tid = threadIdx.x;
    const int lane = tid & 63, wid = tid >> 6;
    const int col = lane & 31, g = lane >> 5;
    const int bid = blockIdx.x;
    const int xg = bid & 15;
    const int c  = (bid >> 4) & 31;
    const int bp = bid >> 9;
    const int xA = xg * 128 + wid * 32 + col;
    const float* xb = x + (bp * NT * NC + c) * NX;
    float* hl = hlds[wid];

    // ---- X: B-pack k-rows g*8+j (f16 hi/lo) + C-rows A(r)=(r&3)+8(r>>2)+4g ----
    f16x8 Xh, Xl;
    float XC[8];
#pragma unroll
    for (int j = 0; j < 8; ++j) {
        const float v = xb[(g * 8 + j) * NC * NX + xA];
        const _Float16 h = (_Float16)v;
        Xh[j] = h; Xl[j] = (_Float16)(v - (float)h);
    }
#pragma unroll
    for (int r = 0; r < 8; ++r) {
        const int A = (r & 3) + 8 * (r >> 2) + 4 * g;
        XC[r] = xb[A * NC * NX + xA];
    }

    // ======== stage 0: h[e] = sqrt_act( X^T G0[c,e] X ), e-pairs ========
    {
        const uint4* p0 = AF0 + (c * 8) * 128;
#pragma unroll 1
        for (int m = 0; m < 8; ++m) {
            const f16x8 Ah = frag_cast(p0[lane]);
            const f16x8 Al = frag_cast(p0[64 + lane]);
            p0 += 128;
            f32x16 C = zero16();
            C = __builtin_amdgcn_mfma_f32_32x32x16_f16(Ah, Xh, C, 0, 0, 0);
            C = __builtin_amdgcn_mfma_f32_32x32x16_f16(Ah, Xl, C, 0, 0, 0);
            C = __builtin_amdgcn_mfma_f32_32x32x16_f16(Al, Xh, C, 0, 0, 0);
            C = __builtin_amdgcn_mfma_f32_32x32x16_f16(Al, Xl, C, 0, 0, 0);
            float se = 0.f, so = 0.f;
#pragma unroll
            for (int r = 0; r < 8; ++r) {
                se += XC[r] * C[r];
                so += XC[r] * C[r + 8];
            }
            se += __shfl_xor(se, 32);
            so += __shfl_xor(so, 32);
            hl[col * HS + 2 * m]     = sqrt_act(se);
            hl[col * HS + 2 * m + 1] = sqrt_act(so);
        }
    }

    // ---- h -> B-packs (k=g*8+j) + C-copies (rows A(r)) from LDS ----
    f16x8 hH, hL;
    float hC[8];
#pragma unroll
    for (int j = 0; j < 8; ++j) {
        const float v = hl[col * HS + g * 8 + j];
        const _Float16 h = (_Float16)v;
        hH[j] = h; hL[j] = (_Float16)(v - (float)h);
    }
#pragma unroll
    for (int r = 0; r < 8; ++r)
        hC[r] = hl[col * HS + (r & 3) + 8 * (r >> 2) + 4 * g];

    // ======== stages 1+2 (e-pairs): pe = a[e,x]*sqrt_act(h^T G1[e] h);
    //          b2[E] += pe_even*U_even[E] + pe_odd*U_odd[E], U = M1t-pair . h
    float b2[8];
#pragma unroll
    for (int r = 0; r < 8; ++r) b2[r] = 0.f;
    {
        const uint4* pG = AFG1;
        const uint4* pM = AFM1;
        const float* pa = a + xA;
#pragma unroll 1
        for (int m = 0; m < 8; ++m) {
            const f16x8 GH = frag_cast(pG[lane]);
            const f16x8 GL = frag_cast(pG[64 + lane]);
            const f16x8 MH = frag_cast(pM[lane]);
            const f16x8 ML = frag_cast(pM[64 + lane]);
            pG += 128; pM += 128;
            const float ae = pa[0], ao = pa[NX];
            pa += 2 * NX;
            f32x16 C = zero16();
            C = __builtin_amdgcn_mfma_f32_32x32x16_f16(GH, hH, C, 0, 0, 0);
            C = __builtin_amdgcn_mfma_f32_32x32x16_f16(GH, hL, C, 0, 0, 0);
            C = __builtin_amdgcn_mfma_f32_32x32x16_f16(GL, hH, C, 0, 0, 0);
            C = __builtin_amdgcn_mfma_f32_32x32x16_f16(GL, hL, C, 0, 0, 0);
            float se = 0.f, so = 0.f;
#pragma unroll
            for (int r = 0; r < 8; ++r) {
                se += hC[r] * C[r];
                so += hC[r] * C[r + 8];
            }
            se += __shfl_xor(se, 32);
            so += __shfl_xor(so, 32);
            const float pe = ae * sqrt_act(se);
            const float po = ao * sqrt_act(so);
            f32x16 U = zero16();
            U = __builtin_amdgcn_mfma_f32_32x32x16_f16(MH, hH, U, 0, 0, 0);
            U = __builtin_amdgcn_mfma_f32_32x32x16_f16(MH, hL, U, 0, 0, 0);
            U = __builtin_amdgcn_mfma_f32_32x32x16_f16(ML, hH, U, 0, 0, 0);
            U = __builtin_amdgcn_mfma_f32_32x32x16_f16(ML, hL, U, 0, 0, 0);
#pragma unroll
            for (int r = 0; r < 8; ++r)
                b2[r] += pe * U[r] + po * U[r + 8];
        }
    }

    // ---- b2 (E-slots E(r)=(r&3)+8((r>>2)&1)+4g) -> LDS -> B-packs (k=E) ----
#pragma unroll
    for (int r = 0; r < 4; ++r) {
        hl[col * HS + r + 4 * g]     = b2[r];        // E = r + 4g
        hl[col * HS + 8 + r + 4 * g] = b2[r + 4];    // E = 8 + r + 4g
    }
    f16x8 bH, bL;
#pragma unroll
    for (int j = 0; j < 8; ++j) {
        const float v = hl[col * HS + g * 8 + j];
        const _Float16 h = (_Float16)v;
        bH[j] = h; bL[j] = (_Float16)(v - (float)h);
    }

    // ======== stage 3 (T-pairs): y += w[T,x] * ( X^T (M2[c,T] . b2) ) ========
    // ^32-reduce deferred out of the loop (w identical for lane and lane^32).
    float ya = 0.f;
    {
        const uint4* p2 = AFM2 + (c * 8) * 128;
        const float* pw = w + xA;
#pragma unroll 1
        for (int m = 0; m < 8; ++m) {
            const f16x8 MH = frag_cast(p2[lane]);
            const f16x8 ML = frag_cast(p2[64 + lane]);
            p2 += 128;
            const float we = pw[0], wo = pw[NX];
            pw += 2 * NX;
            f32x16 Z = zero16();
            Z = __builtin_amdgcn_mfma_f32_32x32x16_f16(MH, bH, Z, 0, 0, 0);
            Z = __builtin_amdgcn_mfma_f32_32x32x16_f16(MH, bL, Z, 0, 0, 0);
            Z = __builtin_amdgcn_mfma_f32_32x32x16_f16(ML, bH, Z, 0, 0, 0);
            Z = __builtin_amdgcn_mfma_f32_32x32x16_f16(ML, bL, Z, 0, 0, 0);
            float se = 0.f, so = 0.f;
#pragma unroll
            for (int r = 0; r < 8; ++r) {
                se += XC[r] * Z[r];
                so += XC[r] * Z[r + 8];
            }
            ya += we * se + wo * so;
        }
    }

    // ---- reduce: ^32 once (deferred), then the 32 columns, then block ----
    float y = ya + __shfl_xor(ya, 32);
    y += __shfl_xor(y, 1); y += __shfl_xor(y, 2);
    y += __shfl_xor(y, 4); y += __shfl_xor(y, 8); y += __shfl_xor(y, 16);
    if (lane == 0) red[wid] = y;
    __syncthreads();
    if (tid == 0) {
        atomicAdd(&out[bp * NC + c], red[0] + red[1] + red[2] + red[3]);
    }
}

extern "C" void kernel_launch(void* const* d_in, const int* in_sizes, int n_in,
                              void* d_out, int out_size, void* d_ws, size_t ws_size,
                              hipStream_t stream) {
    const float* x   = (const float*)d_in[0];
    const float* K0  = (const float*)d_in[1];
    const float* Q0  = (const float*)d_in[2];
    const float* V0  = (const float*)d_in[3];
    const float* K1  = (const float*)d_in[4];
    const float* Q1  = (const float*)d_in[5];
    const float* V1  = (const float*)d_in[6];
    const float* enc = (const float*)d_in[7];
    const float* dec = (const float*)d_in[8];
    const float* a   = (const float*)d_in[9];
    const float* w   = (const float*)d_in[10];
    float* out = (float*)d_out;

    // Pair-frag tables (128 uint4 per pair: [hi 64][lo 64]); contiguous.
    uint4* AF0  = (uint4*)d_ws;              // 256 pairs * 128 = 32768 (512KB)
    uint4* AFG1 = AF0  + 256 * 128;          // 8 pairs   (16KB)
    uint4* AFM1 = AFG1 + 8 * 128;            // 8 pairs   (16KB)
    uint4* AFM2 = AFM1 + 8 * 128;            // 256 pairs (512KB) + pad (2KB)
    // total ws ~= 1.06 MB

    // out must be zeroed every call (harness re-poisons with 0xAA)
    hipMemsetAsync(d_out, 0, (size_t)out_size * sizeof(float), stream);

    precompute_all<<<529, 256, 0, stream>>>(K0, V0, K1, V1, Q0, Q1,
                                            enc, dec, AF0, AFG1, AFM1, AFM2);

    const int nblocks = NB * NP * NC * (NX / 128);  // 8*32*16 = 4096
    site_kernel<<<nblocks, 256, 0, stream>>>(x, a, w, AF0, AFG1, AFM1, AFM2, out);
}

// Round 9
// 168.354 us; speedup vs baseline: 3.4387x; 1.0678x over previous
//
#include <hip/hip_runtime.h>
#include <math.h>

// Problem constants (reference: B,P,NTIME,NLATENT,NSPATIAL = 4,2,16,32,2048)
#define NB 4
#define NP 2
#define NT 16
#define NC 32
#define NX 2048
#define HS 20   // LDS per-column stride (floats): 16B-aligned reads, bank-spread

// ---------------------------------------------------------------------------
// R20 = R19 (validated 105us site, absmax 2.4e-7) + three changes:
//  1. PRECOMPUTE PARALLELIZED: G0/G1 one-e-per-block (512/16 blocks) instead
//     of two serial g_computes (8 syncthreads) per block — halves the
//     latency-dominated critical path. (Total-dur gap was 75us vs site 105.)
//  2. memset folded into precompute pad block (out = 256 floats) — one less
//     stream op in the graph.
//  3. 3-MFMA split: drop the Al*Bl term (<=2^-24 relative: product of two
//     f16 rounding residuals). Issue ports near saturation (63% VALU + 30%
//     MFMA ≈ 93%): cutting MFMA 25% frees issue slots. Predicted absmax
//     ~3-8e-7 vs threshold 1.26e-6.
// Engine (R19): 32x32x16 MFMA, stacked e-pairs, A=[M_2m;M_2m+1],
// one x-site per lane, ONE shfl_xor(32) per e. Layouts HW-verified
// (C: col=lane&31, row=(reg&3)+8(reg>>2)+4(lane>>5), m74/m101).
// Ledger: readlane=VALU-bound(R11); s_load=latency-bound(R13); LDS
// broadcast=DS-bound(R15); 16x16 MFMA=glue-bound(R16-18, 26% MfmaUtil).
// ---------------------------------------------------------------------------

typedef _Float16 f16x8 __attribute__((ext_vector_type(8)));
typedef float f32x16 __attribute__((ext_vector_type(16)));

__device__ __forceinline__ unsigned short f16hi_bits(float v) {
    _Float16 h = (_Float16)v;
    return __builtin_bit_cast(unsigned short, h);
}
__device__ __forceinline__ unsigned short f16lo_bits(float v) {
    _Float16 h = (_Float16)v;
    _Float16 l = (_Float16)(v - (float)h);
    return __builtin_bit_cast(unsigned short, l);
}
__device__ __forceinline__ f16x8 frag_cast(uint4 u) {
    return __builtin_bit_cast(f16x8, u);
}
__device__ __forceinline__ float sqrt_act(float v) {
    return copysignf(sqrtf(fabsf(v)), v);
}
__device__ __forceinline__ f32x16 zero16() {
    f32x16 z;
#pragma unroll
    for (int i = 0; i < 16; ++i) z[i] = 0.f;
    return z;
}

// ---------------------------------------------------------------------------
// Precompute. Pair-frag layout (consumed by site_kernel, unchanged bytes):
// pair m: A-rows 0-15 = matrix 2m, rows 16-31 = matrix 2m+1. Per pair 128
// uint4 = [hi 64 lanes][lo 64 lanes]; lane: row=lane&31, k=(lane>>5)*8+j.
//  blocks [0,512)   : G0, ONE e per block (c=b>>4, e=b&15)
//  blocks [512,528) : G1, one e per block
//  blocks [528,536) : M1t pairs
//  blocks [536,792) : M2 pairs
//  block  792       : zero pad pair + zero out[256]
// ---------------------------------------------------------------------------
__device__ void g_compute(const float* __restrict__ K,
                          const float* __restrict__ V,
                          const float* __restrict__ enc,
                          int cstride, int c, int e, int tid,
                          float* sK, float* sV, float* sE, float* sW,
                          float* outG) {
    {
        const int t = tid >> 4, A = tid & 15;
        sK[tid] = K[(t * 16 + A) * cstride + c];
        sV[tid] = V[(t * 16 + A) * cstride + c];
        sE[tid] = enc[(e * 16 + t) * 16 + A];
    }
    __syncthreads();
    {   // W[t,B] = sum_T enc[e,t,T] * V[T,B,c]
        const int t = tid >> 4, Bi = tid & 15;
        float acc = 0.f;
#pragma unroll
        for (int T = 0; T < 16; ++T) acc += sE[t * 16 + T] * sV[T * 16 + Bi];
        sW[tid] = acc;
    }
    __syncthreads();
    {   // G[A,B] = sum_t K[t,A,c] * W[t,B]   (quadratic form: orientation-immune)
        const int A = tid >> 4, Bi = tid & 15;
        float acc = 0.f;
#pragma unroll
        for (int t = 0; t < 16; ++t) acc += sK[t * 16 + A] * sW[t * 16 + Bi];
        outG[tid] = acc;
    }
    __syncthreads();
}

// Emit ONE matrix's half of a pair-frag: rows [16*half, 16*half+16).
// 64 threads: row=t&15, g=(t>>4)&1, part=t>>5; lane = g*32 + 16*half + row.
__device__ void emit_half(const float* sG, uint4* __restrict__ dstPair,
                          int half, int tid) {
    if (tid < 64) {
        const int row = tid & 15, g = (tid >> 4) & 1, part = tid >> 5;
        unsigned dw[4];
#pragma unroll
        for (int d = 0; d < 4; ++d) {
            const float v0 = sG[row * 16 + g * 8 + 2 * d];
            const float v1 = sG[row * 16 + g * 8 + 2 * d + 1];
            const unsigned short s0 = part ? f16lo_bits(v0) : f16hi_bits(v0);
            const unsigned short s1 = part ? f16lo_bits(v1) : f16hi_bits(v1);
            dw[d] = (unsigned)s0 | ((unsigned)s1 << 16);
        }
        dstPair[part * 64 + g * 32 + 16 * half + row] =
            make_uint4(dw[0], dw[1], dw[2], dw[3]);
    }
}

__global__ __launch_bounds__(256) void precompute_all(
    const float* __restrict__ K0, const float* __restrict__ V0,
    const float* __restrict__ K1, const float* __restrict__ V1,
    const float* __restrict__ Q0, const float* __restrict__ Q1,
    const float* __restrict__ enc, const float* __restrict__ dec,
    uint4* __restrict__ AF0, uint4* __restrict__ AFG1,
    uint4* __restrict__ AFM1, uint4* __restrict__ AFM2,
    float* __restrict__ out) {
    __shared__ float sK[256], sV[256], sE[256], sW[256], sG[256];
    const int b = blockIdx.x, tid = threadIdx.x;
    if (b < 512) {
        const int c = b >> 4, e = b & 15;
        g_compute(K0, V0, enc, NC, c, e, tid, sK, sV, sE, sW, sG);
        emit_half(sG, AF0 + (c * 8 + (e >> 1)) * 128, e & 1, tid);
    } else if (b < 528) {
        const int e = b - 512;
        g_compute(K1, V1, enc, 1, 0, e, tid, sK, sV, sE, sW, sG);
        emit_half(sG, AFG1 + (e >> 1) * 128, e & 1, tid);
    } else if (b < 536) {
        // M1t[e][E][T] = sum_t Q1[t,T]*dec[e,t,E]; pair rows=E, k=T
        const int m = b - 528;
        if (tid < 128) {
            const int part = tid >> 6, lane = tid & 63;
            const int row32 = lane & 31, g = lane >> 5;
            const int e = 2 * m + (row32 >> 4), E = row32 & 15;
            unsigned dw[4];
#pragma unroll
            for (int d = 0; d < 4; ++d) {
                unsigned short s01[2];
#pragma unroll
                for (int hh = 0; hh < 2; ++hh) {
                    const int T = g * 8 + 2 * d + hh;
                    float acc = 0.f;
#pragma unroll
                    for (int t = 0; t < 16; ++t)
                        acc += Q1[t * 16 + T] * dec[(e * 16 + t) * 16 + E];
                    s01[hh] = part ? f16lo_bits(acc) : f16hi_bits(acc);
                }
                dw[d] = (unsigned)s01[0] | ((unsigned)s01[1] << 16);
            }
            AFM1[m * 128 + part * 64 + lane] = make_uint4(dw[0], dw[1], dw[2], dw[3]);
        }
    } else if (b < 792) {
        // M2[c][T][A][E] = sum_t Q0[t,A,c]*dec[E,t,T]; pair rows=A (T-pair), k=E
        const int idx = b - 536;
        const int c = idx >> 3, m = idx & 7;
        if (tid < 128) {
            const int part = tid >> 6, lane = tid & 63;
            const int row32 = lane & 31, g = lane >> 5;
            const int T = 2 * m + (row32 >> 4), A = row32 & 15;
            unsigned dw[4];
#pragma unroll
            for (int d = 0; d < 4; ++d) {
                unsigned short s01[2];
#pragma unroll
                for (int hh = 0; hh < 2; ++hh) {
                    const int E = g * 8 + 2 * d + hh;
                    float acc = 0.f;
#pragma unroll
                    for (int t = 0; t < 16; ++t)
                        acc += Q0[(t * 16 + A) * NC + c] * dec[(E * 16 + t) * 16 + T];
                    s01[hh] = part ? f16lo_bits(acc) : f16hi_bits(acc);
                }
                dw[d] = (unsigned)s01[0] | ((unsigned)s01[1] << 16);
            }
            AFM2[(c * 8 + m) * 128 + part * 64 + lane] =
                make_uint4(dw[0], dw[1], dw[2], dw[3]);
        }
    } else {
        // zero pad pair (prefetch overrun target) + zero the output buffer
        if (tid < 128) AFM2[256 * 128 + tid] = make_uint4(0u, 0u, 0u, 0u);
        out[tid] = 0.f;   // out = NB*NP*NC = 256 floats, tid covers exactly
    }
}

// ---------------------------------------------------------------------------
// Main kernel: one WAVE = 32 x-sites (one per lane, col=lane&31) of one
// (bp,c). Block = 4 waves = 128 x. grid = 4096; consecutive blocks share
// (bp,c) -> frag tables L2/L1-hot. 3-MFMA split product per matvec-pair:
// MhVh + MhVl + MlVh (MlVl <= 2^-24 rel, dropped).
// ---------------------------------------------------------------------------
__global__ __launch_bounds__(256) void site_kernel(
    const float* __restrict__ x,
    const float* __restrict__ a,
    const float* __restrict__ w,
    const uint4* __restrict__ AF0,
    const uint4* __restrict__ AFG1,
    const uint4* __restrict__ AFM1,
    const uint4* __restrict__ AFM2,
    float* __restrict__ out) {
    __shared__ float hlds[4][32 * HS];
    __shared__ float red[4];

    const int tid = threadIdx.x;
    const int lane = tid & 63, wid = tid >> 6;
    const int col = lane & 31, g = lane >> 5;
    const int bid = blockIdx.x;
    const int xg = bid & 15;
    const int c  = (bid >> 4) & 31;
    const int bp = bid >> 9;
    const int xA = xg * 128 + wid * 32 + col;
    const float* xb = x + (bp * NT * NC + c) * NX;
    float* hl = hlds[wid];

    // ---- X: B-pack k-rows g*8+j (f16 hi/lo) + C-rows A(r)=(r&3)+8(r>>2)+4g ----
    f16x8 Xh, Xl;
    float XC[8];
#pragma unroll
    for (int j = 0; j < 8; ++j) {
        const float v = xb[(g * 8 + j) * NC * NX + xA];
        const _Float16 h = (_Float16)v;
        Xh[j] = h; Xl[j] = (_Float16)(v - (float)h);
    }
#pragma unroll
    for (int r = 0; r < 8; ++r) {
        const int A = (r & 3) + 8 * (r >> 2) + 4 * g;
        XC[r] = xb[A * NC * NX + xA];
    }

    // ======== stage 0: h[e] = sqrt_act( X^T G0[c,e] X ), e-pairs ========
    {
        const uint4* p0 = AF0 + (c * 8) * 128;
#pragma unroll 1
        for (int m = 0; m < 8; ++m) {
            const f16x8 Ah = frag_cast(p0[lane]);
            const f16x8 Al = frag_cast(p0[64 + lane]);
            p0 += 128;
            f32x16 C = zero16();
            C = __builtin_amdgcn_mfma_f32_32x32x16_f16(Ah, Xh, C, 0, 0, 0);
            C = __builtin_amdgcn_mfma_f32_32x32x16_f16(Ah, Xl, C, 0, 0, 0);
            C = __builtin_amdgcn_mfma_f32_32x32x16_f16(Al, Xh, C, 0, 0, 0);
            float se = 0.f, so = 0.f;
#pragma unroll
            for (int r = 0; r < 8; ++r) {
                se += XC[r] * C[r];
                so += XC[r] * C[r + 8];
            }
            se += __shfl_xor(se, 32);
            so += __shfl_xor(so, 32);
            hl[col * HS + 2 * m]     = sqrt_act(se);
            hl[col * HS + 2 * m + 1] = sqrt_act(so);
        }
    }

    // ---- h -> B-packs (k=g*8+j) + C-copies (rows A(r)) from LDS ----
    f16x8 hH, hL;
    float hC[8];
#pragma unroll
    for (int j = 0; j < 8; ++j) {
        const float v = hl[col * HS + g * 8 + j];
        const _Float16 h = (_Float16)v;
        hH[j] = h; hL[j] = (_Float16)(v - (float)h);
    }
#pragma unroll
    for (int r = 0; r < 8; ++r)
        hC[r] = hl[col * HS + (r & 3) + 8 * (r >> 2) + 4 * g];

    // ======== stages 1+2 (e-pairs): pe = a[e,x]*sqrt_act(h^T G1[e] h);
    //          b2[E] += pe_even*U_even[E] + pe_odd*U_odd[E], U = M1t-pair . h
    float b2[8];
#pragma unroll
    for (int r = 0; r < 8; ++r) b2[r] = 0.f;
    {
        const uint4* pG = AFG1;
        const uint4* pM = AFM1;
        const float* pa = a + xA;
#pragma unroll 1
        for (int m = 0; m < 8; ++m) {
            const f16x8 GH = frag_cast(pG[lane]);
            const f16x8 GL = frag_cast(pG[64 + lane]);
            const f16x8 MH = frag_cast(pM[lane]);
            const f16x8 ML = frag_cast(pM[64 + lane]);
            pG += 128; pM += 128;
            const float ae = pa[0], ao = pa[NX];
            pa += 2 * NX;
            f32x16 C = zero16();
            C = __builtin_amdgcn_mfma_f32_32x32x16_f16(GH, hH, C, 0, 0, 0);
            C = __builtin_amdgcn_mfma_f32_32x32x16_f16(GH, hL, C, 0, 0, 0);
            C = __builtin_amdgcn_mfma_f32_32x32x16_f16(GL, hH, C, 0, 0, 0);
            float se = 0.f, so = 0.f;
#pragma unroll
            for (int r = 0; r < 8; ++r) {
                se += hC[r] * C[r];
                so += hC[r] * C[r + 8];
            }
            se += __shfl_xor(se, 32);
            so += __shfl_xor(so, 32);
            const float pe = ae * sqrt_act(se);
            const float po = ao * sqrt_act(so);
            f32x16 U = zero16();
            U = __builtin_amdgcn_mfma_f32_32x32x16_f16(MH, hH, U, 0, 0, 0);
            U = __builtin_amdgcn_mfma_f32_32x32x16_f16(MH, hL, U, 0, 0, 0);
            U = __builtin_amdgcn_mfma_f32_32x32x16_f16(ML, hH, U, 0, 0, 0);
#pragma unroll
            for (int r = 0; r < 8; ++r)
                b2[r] += pe * U[r] + po * U[r + 8];
        }
    }

    // ---- b2 (E-slots E(r)=(r&3)+8((r>>2)&1)+4g) -> LDS -> B-packs (k=E) ----
#pragma unroll
    for (int r = 0; r < 4; ++r) {
        hl[col * HS + r + 4 * g]     = b2[r];        // E = r + 4g
        hl[col * HS + 8 + r + 4 * g] = b2[r + 4];    // E = 8 + r + 4g
    }
    f16x8 bH, bL;
#pragma unroll
    for (int j = 0; j < 8; ++j) {
        const float v = hl[col * HS + g * 8 + j];
        const _Float16 h = (_Float16)v;
        bH[j] = h; bL[j] = (_Float16)(v - (float)h);
    }

    // ======== stage 3 (T-pairs): y += w[T,x] * ( X^T (M2[c,T] . b2) ) ========
    // ^32-reduce deferred out of the loop (w identical for lane and lane^32).
    float ya = 0.f;
    {
        const uint4* p2 = AFM2 + (c * 8) * 128;
        const float* pw = w + xA;
#pragma unroll 1
        for (int m = 0; m < 8; ++m) {
            const f16x8 MH = frag_cast(p2[lane]);
            const f16x8 ML = frag_cast(p2[64 + lane]);
            p2 += 128;
            const float we = pw[0], wo = pw[NX];
            pw += 2 * NX;
            f32x16 Z = zero16();
            Z = __builtin_amdgcn_mfma_f32_32x32x16_f16(MH, bH, Z, 0, 0, 0);
            Z = __builtin_amdgcn_mfma_f32_32x32x16_f16(MH, bL, Z, 0, 0, 0);
            Z = __builtin_amdgcn_mfma_f32_32x32x16_f16(ML, bH, Z, 0, 0, 0);
            float se = 0.f, so = 0.f;
#pragma unroll
            for (int r = 0; r < 8; ++r) {
                se += XC[r] * Z[r];
                so += XC[r] * Z[r + 8];
            }
            ya += we * se + wo * so;
        }
    }

    // ---- reduce: ^32 once (deferred), then the 32 columns, then block ----
    float y = ya + __shfl_xor(ya, 32);
    y += __shfl_xor(y, 1); y += __shfl_xor(y, 2);
    y += __shfl_xor(y, 4); y += __shfl_xor(y, 8); y += __shfl_xor(y, 16);
    if (lane == 0) red[wid] = y;
    __syncthreads();
    if (tid == 0) {
        atomicAdd(&out[bp * NC + c], red[0] + red[1] + red[2] + red[3]);
    }
}

extern "C" void kernel_launch(void* const* d_in, const int* in_sizes, int n_in,
                              void* d_out, int out_size, void* d_ws, size_t ws_size,
                              hipStream_t stream) {
    const float* x   = (const float*)d_in[0];
    const float* K0  = (const float*)d_in[1];
    const float* Q0  = (const float*)d_in[2];
    const float* V0  = (const float*)d_in[3];
    const float* K1  = (const float*)d_in[4];
    const float* Q1  = (const float*)d_in[5];
    const float* V1  = (const float*)d_in[6];
    const float* enc = (const float*)d_in[7];
    const float* dec = (const float*)d_in[8];
    const float* a   = (const float*)d_in[9];
    const float* w   = (const float*)d_in[10];
    float* out = (float*)d_out;

    // Pair-frag tables (128 uint4 per pair: [hi 64][lo 64]); contiguous.
    uint4* AF0  = (uint4*)d_ws;              // 256 pairs * 128 = 32768 (512KB)
    uint4* AFG1 = AF0  + 256 * 128;          // 8 pairs   (16KB)
    uint4* AFM1 = AFG1 + 8 * 128;            // 8 pairs   (16KB)
    uint4* AFM2 = AFM1 + 8 * 128;            // 256 pairs (512KB) + pad (2KB)
    // total ws ~= 1.06 MB

    // out zeroing folded into precompute block 792 (same-stream ordering
    // guarantees completion before site_kernel's atomics).
    precompute_all<<<793, 256, 0, stream>>>(K0, V0, K1, V1, Q0, Q1,
                                            enc, dec, AF0, AFG1, AFM1, AFM2,
                                            out);

    const int nblocks = NB * NP * NC * (NX / 128);  // 8*32*16 = 4096
    site_kernel<<<nblocks, 256, 0, stream>>>(x, a, w, AF0, AFG1, AFM1, AFM2, out);
}